// Round 9
// baseline (274.707 us; speedup 1.0000x reference)
//
#include <hip/hip_runtime.h>
#include <math.h>

// Problem constants
constexpr int Bc = 8;
constexpr int Lc = 1024;
constexpr int Dc = 512;        // model dim
constexpr int Hc = 8;
constexpr int DHc = 64;
constexpr int DLc = 64;
constexpr int NBc = 128;
constexpr int TOTAL_OUT = 2 * DLc * Hc + 2 * DHc * Hc;  // 2048
constexpr int ROWS = Bc * Lc;  // 8192

using f32x4 = __attribute__((ext_vector_type(4))) float;
using s16x8 = __attribute__((ext_vector_type(8))) short;

__device__ __forceinline__ float bf2f(ushort u) {
    union { unsigned int i; float f; } v; v.i = ((unsigned int)u) << 16; return v.f;
}
__device__ __forceinline__ ushort f2bf(float f) {
    union { float f; unsigned int i; } v; v.f = f;
    unsigned int r = v.i + 0x7fffu + ((v.i >> 16) & 1u);  // RNE
    return (ushort)(r >> 16);
}
// silu via v_exp + v_rcp (1-instr transcendentals) instead of precise divide
__device__ __forceinline__ float silu(float x) {
    float e = __expf(-x);
    return x * __builtin_amdgcn_rcpf(1.0f + e);
}

// ---------------------------------------------------------------------------
// Transpose + cast fp32 (R x C) -> bf16 (C x R)
// ---------------------------------------------------------------------------
__global__ __launch_bounds__(256) void transpose_cast(const float* __restrict__ in,
                                                      ushort* __restrict__ out,
                                                      int R, int C) {
    __shared__ float tile[32][33];
    int bc = blockIdx.x * 32, br = blockIdx.y * 32;
    int tx = threadIdx.x & 31, ty = threadIdx.x >> 5;  // 32x8
    for (int i = ty; i < 32; i += 8) {
        int r = br + i, c = bc + tx;
        tile[i][tx] = (r < R && c < C) ? in[(size_t)r * C + c] : 0.f;
    }
    __syncthreads();
    for (int i = ty; i < 32; i += 8) {
        int c = bc + i, r = br + tx;
        if (c < C && r < R) out[(size_t)c * R + r] = f2bf(tile[tx][i]);
    }
}

// ---------------------------------------------------------------------------
// LN1: x (ROWS x 512 fp32) -> bf16 normalized. One wave per row.
// ---------------------------------------------------------------------------
__global__ __launch_bounds__(256) void ln1_kernel(const float* __restrict__ x,
                                                  const float* __restrict__ g,
                                                  const float* __restrict__ bta,
                                                  ushort* __restrict__ outp) {
    int wid = threadIdx.x >> 6, lane = threadIdx.x & 63;
    int row = blockIdx.x * 4 + wid;
    const float4* xr = (const float4*)(x + (size_t)row * Dc);
    float4 a = xr[lane * 2], c = xr[lane * 2 + 1];
    float xv[8] = {a.x, a.y, a.z, a.w, c.x, c.y, c.z, c.w};
    float s = 0.f, q = 0.f;
#pragma unroll
    for (int i = 0; i < 8; i++) { s += xv[i]; q += xv[i] * xv[i]; }
#pragma unroll
    for (int off = 32; off; off >>= 1) { s += __shfl_xor(s, off); q += __shfl_xor(q, off); }
    float mean = s * (1.f / 512.f);
    float var  = q * (1.f / 512.f) - mean * mean;
    float rstd = rsqrtf(var + 1e-6f);
    const float4* gv = (const float4*)g; const float4* bv = (const float4*)bta;
    float4 g0 = gv[lane * 2], g1 = gv[lane * 2 + 1];
    float4 b0 = bv[lane * 2], b1 = bv[lane * 2 + 1];
    float G[8] = {g0.x, g0.y, g0.z, g0.w, g1.x, g1.y, g1.z, g1.w};
    float Bv[8] = {b0.x, b0.y, b0.z, b0.w, b1.x, b1.y, b1.z, b1.w};
    union { ushort u16[8]; uint4 v; } pk;
#pragma unroll
    for (int i = 0; i < 8; i++) pk.u16[i] = f2bf((xv[i] - mean) * rstd * G[i] + Bv[i]);
    ((uint4*)(outp + (size_t)row * Dc))[lane] = pk.v;
}

// ---------------------------------------------------------------------------
// Bias precompute: bias[b][m][n] = pos_w[L-1+n-m] + ts_w[bucket(ts[m+1]-ts[n])]
// (head-independent -> computed ONCE instead of once per head in attn).
// Grid (L/8, B), 256 thr: thread = (m = bx*8 + tid>>5, n chunk of 32).
// ---------------------------------------------------------------------------
__global__ __launch_bounds__(256) void bias_kernel(const int* __restrict__ ts,
                                                   const float* __restrict__ pos_w,
                                                   const float* __restrict__ ts_w,
                                                   ushort* __restrict__ biasb) {
    __shared__ float posw[2 * Lc - 1];
    __shared__ float tsw[NBc + 1];
    int tid = threadIdx.x;
    int b = blockIdx.y;
    for (int i = tid; i < 2 * Lc - 1; i += 256) posw[i] = pos_w[i];
    if (tid < NBc + 1) tsw[tid] = ts_w[tid];
    __syncthreads();
    int m = blockIdx.x * 8 + (tid >> 5);
    int n0 = (tid & 31) * 32;
    const int* tsb = ts + b * Lc;
    int mp = m + 1 < Lc ? m + 1 : Lc - 1;
    int tsm = tsb[mp];
    int pbase = (Lc - 1) + n0 - m;
    union { ushort u16[32]; uint4 v[4]; } o;
#pragma unroll
    for (int i = 0; i < 32; i += 4) {
        int4 tn = *(const int4*)&tsb[n0 + i];
        int dv[4] = {tsm - tn.x, tsm - tn.y, tsm - tn.z, tsm - tn.w};
#pragma unroll
        for (int e = 0; e < 4; e++) {
            float mag = fmaxf(fabsf((float)dv[e]), 1.f);
            int bkt = (int)(__log2f(mag) * 2.3028147f);  // ln(mag)/0.301
            bkt = bkt < 0 ? 0 : (bkt > NBc ? NBc : bkt);
            o.u16[i + e] = f2bf(posw[pbase + i + e] + tsw[bkt]);
        }
    }
    uint4* dst = (uint4*)&biasb[((size_t)b * Lc + m) * Lc + n0];
#pragma unroll
    for (int i = 0; i < 4; i++) dst[i] = o.v[i];
}

// ---------------------------------------------------------------------------
// GEMM1: X1 (8192x512 bf16) @ W1T^T -> silu -> split-store:
//   u, q, k row-major (8192x512 each); V TRANSPOSED: VT[(b*8+h)*64+d][n] (64 heads)
// ---------------------------------------------------------------------------
__global__ __launch_bounds__(256) void gemm1_kernel(const ushort* __restrict__ A,
                                                    const ushort* __restrict__ Bt,
                                                    ushort* __restrict__ Ub,
                                                    ushort* __restrict__ VTg,
                                                    ushort* __restrict__ Qb,
                                                    ushort* __restrict__ Kb) {
    __shared__ __align__(16) ushort As[128][72];
    __shared__ __align__(16) ushort Bs[128][72];
    int tid = threadIdx.x;
    int m0 = blockIdx.x * 128, n0 = blockIdx.y * 128;
    int w = tid >> 6, lane = tid & 63;
    int wm = (w >> 1) * 64, wn = (w & 1) * 64;
    f32x4 acc[4][4] = {};
    for (int k0 = 0; k0 < Dc; k0 += 64) {
        __syncthreads();
#pragma unroll
        for (int c = tid; c < 1024; c += 256) {
            int r = c >> 3, c8 = c & 7;
            *(uint4*)&As[r][c8 * 8] = *(const uint4*)&A[(size_t)(m0 + r) * Dc + k0 + c8 * 8];
            *(uint4*)&Bs[r][c8 * 8] = *(const uint4*)&Bt[(size_t)(n0 + r) * Dc + k0 + c8 * 8];
        }
        __syncthreads();
#pragma unroll
        for (int ks = 0; ks < 2; ++ks) {
            int kb = ks * 32 + (lane >> 4) * 8;
            s16x8 af[4], bfr[4];
#pragma unroll
            for (int i = 0; i < 4; i++) af[i] = *(const s16x8*)&As[wm + i * 16 + (lane & 15)][kb];
#pragma unroll
            for (int j = 0; j < 4; j++) bfr[j] = *(const s16x8*)&Bs[wn + j * 16 + (lane & 15)][kb];
#pragma unroll
            for (int i = 0; i < 4; i++)
#pragma unroll
                for (int j = 0; j < 4; j++)
                    acc[i][j] = __builtin_amdgcn_mfma_f32_16x16x32_bf16(af[i], bfr[j], acc[i][j], 0, 0, 0);
        }
    }
    int lr = (lane >> 4) * 4, lc = lane & 15;
#pragma unroll
    for (int i = 0; i < 4; i++)
#pragma unroll
        for (int j = 0; j < 4; j++) {
            int col = n0 + wn + j * 16 + lc;
            int sect = col >> 9, cc = col & 511;
            int row0 = m0 + wm + i * 16 + lr;
            if (sect == 1) {
                // V: transposed store. rows row0..row0+3 -> n consecutive
                int hh = cc >> 6, dd = cc & 63;
                int bb = row0 >> 10, nn = row0 & 1023;
                ushort4 pk;
                pk.x = f2bf(silu(acc[i][j][0]));
                pk.y = f2bf(silu(acc[i][j][1]));
                pk.z = f2bf(silu(acc[i][j][2]));
                pk.w = f2bf(silu(acc[i][j][3]));
                *(ushort4*)&VTg[((size_t)((bb * 8 + hh) * 64 + dd)) * 1024 + nn] = pk;
            } else {
                ushort* dst = (sect == 0) ? Ub : (sect == 2) ? Qb : Kb;
#pragma unroll
                for (int r = 0; r < 4; r++)
                    dst[(size_t)(row0 + r) * 512 + cc] = f2bf(silu(acc[i][j][r]));
            }
        }
}

// ---------------------------------------------------------------------------
// Fused causal attention, pipelined, bias from precomputed table.
// Grid (16, H, B): 64 M-rows/block, 4 waves x 16 rows.
// K double-buffered in LDS (reg-staged, XOR-swizzled, write after PV).
// V^T and bias prefetched direct from global at iteration top.
// ---------------------------------------------------------------------------
__global__ __launch_bounds__(256) void attn_kernel(const ushort* __restrict__ Qb,
                                                   const ushort* __restrict__ Kb,
                                                   const ushort* __restrict__ VTg,
                                                   const ushort* __restrict__ biasb,
                                                   ushort* __restrict__ Ob) {
    int bx = blockIdx.x;
    int mt = (bx & 1) ? (bx >> 1) : (15 - (bx >> 1));  // pairwise balance 0..15
    int h = blockIdx.y, b = blockIdx.z;
    __shared__ __align__(16) ushort Ks[2][64][64];   // 16 KB, XOR-swizzled slots
    __shared__ __align__(16) ushort Ps[4][16][72];   // 9 KB, per-wave P bounce
    int tid = threadIdx.x, w = tid >> 6, lane = tid & 63;
    const size_t qkbase = ((size_t)b * Lc) * 512 + h * 64;
    const size_t vtbase = ((size_t)((b * 8 + h) * 64)) * 1024;
    const ushort* biasB = biasb + (size_t)b * Lc * Lc;
    const int m0 = mt * 64;
    int lc = lane & 15, g4 = lane >> 4, lr = g4 * 4;
    // --- K staging geometry: thread t covers 32B of the 8KB tile ---
    int sr = tid >> 2;               // tile row 0..63
    int ss0 = (tid & 3) * 2;         // 16B-slot 0,2,4,6
    const ushort* kgrow = Kb + qkbase + (size_t)sr * 512;
    int dso0 = sr * 64 + (((ss0)     ^ (sr & 7)) * 8);
    int dso1 = sr * 64 + (((ss0 + 1) ^ (sr & 7)) * 8);

    // prologue: stage K(0) into Ks[0]
    {
        uint4 ka = *(const uint4*)(kgrow + ss0 * 8);
        uint4 kb_ = *(const uint4*)(kgrow + (ss0 + 1) * 8);
        *(uint4*)&(&Ks[0][0][0])[dso0] = ka;
        *(uint4*)&(&Ks[0][0][0])[dso1] = kb_;
    }
    __syncthreads();

    // Q fragments for this wave's 16 rows
    s16x8 qf[2];
#pragma unroll
    for (int ks = 0; ks < 2; ++ks)
        qf[ks] = *(const s16x8*)&Qb[qkbase + (size_t)(m0 + w * 16 + lc) * 512 + ks * 32 + g4 * 8];
    int mbase = m0 + w * 16 + lr;

    f32x4 acc_o[4] = {};
    int ntiles = mt + 1;
    int cur = 0;
    for (int nt = 0; nt < ntiles; ++nt) {
        int n0 = nt * 64;
        // prefetch V^T fragments for THIS tile (consumed at bottom)
        s16x8 vb[2][4];
#pragma unroll
        for (int ks = 0; ks < 2; ++ks)
#pragma unroll
            for (int j = 0; j < 4; j++)
                vb[ks][j] = *(const s16x8*)&VTg[vtbase + (size_t)(j * 16 + lc) * 1024 + n0 + ks * 32 + g4 * 8];
        // prefetch bias bf16 for this lane's 16 elements (consumed mid-iter)
        ushort bsv[4][4];
#pragma unroll
        for (int j = 0; j < 4; j++)
#pragma unroll
            for (int r = 0; r < 4; r++)
                bsv[j][r] = biasB[(size_t)(mbase + r) * Lc + n0 + j * 16 + lc];
        // prefetch K(nt+1) into regs (ds_write after PV)
        bool hasnext = (nt + 1 < ntiles);
        uint4 ka = {}, kb_ = {};
        if (hasnext) {
            const ushort* kgn = kgrow + (size_t)(n0 + 64) * 512;
            ka  = *(const uint4*)(kgn + ss0 * 8);
            kb_ = *(const uint4*)(kgn + (ss0 + 1) * 8);
        }
        // S = Q K^T from swizzled LDS
        const ushort* ksb = &Ks[cur][0][0];
        f32x4 s[4] = {};
#pragma unroll
        for (int ks = 0; ks < 2; ++ks) {
            s16x8 kf[4];
#pragma unroll
            for (int j = 0; j < 4; j++)
                kf[j] = *(const s16x8*)&ksb[(j * 16 + lc) * 64 + (((ks * 4 + g4) ^ (lc & 7)) * 8)];
#pragma unroll
            for (int j = 0; j < 4; j++)
                s[j] = __builtin_amdgcn_mfma_f32_16x16x32_bf16(qf[ks], kf[j], s[j], 0, 0, 0);
        }
        // + bias, silu, causal mask (only diagonal tile needs the mask)
        bool diag = (nt == mt);
#pragma unroll
        for (int j = 0; j < 4; j++)
#pragma unroll
            for (int r = 0; r < 4; r++) {
                float sv = s[j][r] + bf2f(bsv[j][r]);
                float val = silu(sv) * (1.f / (float)Lc);
                if (diag && (j * 16 + lc) > (w * 16 + lr + r)) val = 0.f;
                Ps[w][lr + r][j * 16 + lc] = f2bf(val);
            }
        // O += P V  (P from own LDS rows; vb prefetched at top)
#pragma unroll
        for (int ks = 0; ks < 2; ++ks) {
            s16x8 pa = *(const s16x8*)&Ps[w][lc][ks * 32 + g4 * 8];
#pragma unroll
            for (int j = 0; j < 4; j++)
                acc_o[j] = __builtin_amdgcn_mfma_f32_16x16x32_bf16(pa, vb[ks][j], acc_o[j], 0, 0, 0);
        }
        // stage K(nt+1) into the other buffer
        if (hasnext) {
            ushort* kd = &Ks[cur ^ 1][0][0];
            *(uint4*)&kd[dso0] = ka;
            *(uint4*)&kd[dso1] = kb_;
        }
        __syncthreads();
        cur ^= 1;
    }
#pragma unroll
    for (int j = 0; j < 4; j++)
#pragma unroll
        for (int r = 0; r < 4; r++) {
            int m = mbase + r;
            Ob[qkbase + (size_t)m * 512 + j * 16 + lc] = f2bf(acc_o[j][r]);
        }
}

// ---------------------------------------------------------------------------
// LN2(attn) * u -> bf16. One wave per row.
// ---------------------------------------------------------------------------
__global__ __launch_bounds__(256) void ln2_kernel(const ushort* __restrict__ z,
                                                  const ushort* __restrict__ u,
                                                  const float* __restrict__ g,
                                                  const float* __restrict__ bta,
                                                  ushort* __restrict__ outp) {
    int wid = threadIdx.x >> 6, lane = threadIdx.x & 63;
    int row = blockIdx.x * 4 + wid;
    uint4 zv = ((const uint4*)(z + (size_t)row * 512))[lane];
    ushort* zu = (ushort*)&zv;
    float xv[8], s = 0.f, q = 0.f;
#pragma unroll
    for (int i = 0; i < 8; i++) { xv[i] = bf2f(zu[i]); s += xv[i]; q += xv[i] * xv[i]; }
#pragma unroll
    for (int off = 32; off; off >>= 1) { s += __shfl_xor(s, off); q += __shfl_xor(q, off); }
    float mean = s * (1.f / 512.f);
    float var  = q * (1.f / 512.f) - mean * mean;
    float rstd = rsqrtf(var + 1e-6f);
    uint4 uv = ((const uint4*)(u + (size_t)row * 512))[lane];
    ushort* uu = (ushort*)&uv;
    const float4* gv = (const float4*)g; const float4* bv = (const float4*)bta;
    float4 g0 = gv[lane * 2], g1 = gv[lane * 2 + 1];
    float4 b0 = bv[lane * 2], b1 = bv[lane * 2 + 1];
    float G[8] = {g0.x, g0.y, g0.z, g0.w, g1.x, g1.y, g1.z, g1.w};
    float Bv[8] = {b0.x, b0.y, b0.z, b0.w, b1.x, b1.y, b1.z, b1.w};
    union { ushort u16[8]; uint4 v; } pk;
#pragma unroll
    for (int i = 0; i < 8; i++)
        pk.u16[i] = f2bf(((xv[i] - mean) * rstd * G[i] + Bv[i]) * bf2f(uu[i]));
    ((uint4*)(outp + (size_t)row * 512))[lane] = pk.v;
}

// ---------------------------------------------------------------------------
// GEMM2: A2 (8192x512 bf16) @ W2T^T + out_b + x -> fp32
// ---------------------------------------------------------------------------
__global__ __launch_bounds__(256) void gemm2_kernel(const ushort* __restrict__ A,
                                                    const ushort* __restrict__ Bt,
                                                    const float* __restrict__ ob,
                                                    const float* __restrict__ x,
                                                    float* __restrict__ outp) {
    __shared__ __align__(16) ushort As[128][72];
    __shared__ __align__(16) ushort Bs[128][72];
    int tid = threadIdx.x;
    int m0 = blockIdx.x * 128, n0 = blockIdx.y * 128;
    int w = tid >> 6, lane = tid & 63;
    int wm = (w >> 1) * 64, wn = (w & 1) * 64;
    f32x4 acc[4][4] = {};
    for (int k0 = 0; k0 < Dc; k0 += 64) {
        __syncthreads();
#pragma unroll
        for (int c = tid; c < 1024; c += 256) {
            int r = c >> 3, c8 = c & 7;
            *(uint4*)&As[r][c8 * 8] = *(const uint4*)&A[(size_t)(m0 + r) * Dc + k0 + c8 * 8];
            *(uint4*)&Bs[r][c8 * 8] = *(const uint4*)&Bt[(size_t)(n0 + r) * Dc + k0 + c8 * 8];
        }
        __syncthreads();
#pragma unroll
        for (int ks = 0; ks < 2; ++ks) {
            int kb = ks * 32 + (lane >> 4) * 8;
            s16x8 af[4], bfr[4];
#pragma unroll
            for (int i = 0; i < 4; i++) af[i] = *(const s16x8*)&As[wm + i * 16 + (lane & 15)][kb];
#pragma unroll
            for (int j = 0; j < 4; j++) bfr[j] = *(const s16x8*)&Bs[wn + j * 16 + (lane & 15)][kb];
#pragma unroll
            for (int i = 0; i < 4; i++)
#pragma unroll
                for (int j = 0; j < 4; j++)
                    acc[i][j] = __builtin_amdgcn_mfma_f32_16x16x32_bf16(af[i], bfr[j], acc[i][j], 0, 0, 0);
        }
    }
    int lr = (lane >> 4) * 4, lc = lane & 15;
#pragma unroll
    for (int i = 0; i < 4; i++)
#pragma unroll
        for (int j = 0; j < 4; j++) {
            int col = n0 + wn + j * 16 + lc;
            float bias = ob[col];
#pragma unroll
            for (int r = 0; r < 4; r++) {
                int row = m0 + wm + i * 16 + lr + r;
                size_t off = (size_t)row * 512 + col;
                outp[off] = acc[i][j][r] + bias + x[off];
            }
        }
}

// ---------------------------------------------------------------------------
extern "C" void kernel_launch(void* const* d_in, const int* in_sizes, int n_in,
                              void* d_out, int out_size, void* d_ws, size_t ws_size,
                              hipStream_t stream) {
    const float* x      = (const float*)d_in[0];
    const int*   tsp    = (const int*)d_in[1];
    // d_in[2]: attn_mask (implicit causal; unused)
    const float* uvqk_w = (const float*)d_in[3];
    const float* out_w  = (const float*)d_in[4];
    const float* out_b  = (const float*)d_in[5];
    const float* ln1_g  = (const float*)d_in[6];
    const float* ln1_b  = (const float*)d_in[7];
    const float* ln2_g  = (const float*)d_in[8];
    const float* ln2_b  = (const float*)d_in[9];
    const float* ts_w   = (const float*)d_in[10];
    const float* pos_w  = (const float*)d_in[11];
    float* outp = (float*)d_out;

    char* ws = (char*)d_ws;
    size_t off = 0;
    auto alloc = [&](size_t bytes) { char* p = ws + off; off += (bytes + 255) & ~(size_t)255; return p; };
    const size_t MAT = (size_t)ROWS * 512 * sizeof(ushort);  // 8 MB
    ushort* W1T = (ushort*)alloc((size_t)TOTAL_OUT * Dc * 2);  // 2 MB
    ushort* W2T = (ushort*)alloc((size_t)Dc * Dc * 2);         // 0.5 MB
    ushort* X1  = (ushort*)alloc(MAT);
    ushort* Ub  = (ushort*)alloc(MAT);
    ushort* VTg = (ushort*)alloc(MAT);  // V transposed: [(b*8+h)*64+d][n]
    ushort* Qb  = (ushort*)alloc(MAT);
    ushort* Kb  = (ushort*)alloc(MAT);
    ushort* Ob  = (ushort*)alloc(MAT);
    ushort* BIAS = (ushort*)alloc((size_t)Bc * Lc * Lc * 2);  // 16.8 MB
    ushort* A2  = X1;  // X1 dead after gemm1 -> reuse for ln2 output

    transpose_cast<<<dim3(TOTAL_OUT / 32, Dc / 32), 256, 0, stream>>>(uvqk_w, W1T, Dc, TOTAL_OUT);
    transpose_cast<<<dim3(Dc / 32, Dc / 32), 256, 0, stream>>>(out_w, W2T, Dc, Dc);
    bias_kernel<<<dim3(Lc / 8, Bc), 256, 0, stream>>>(tsp, pos_w, ts_w, BIAS);
    ln1_kernel<<<ROWS / 4, 256, 0, stream>>>(x, ln1_g, ln1_b, X1);
    gemm1_kernel<<<dim3(ROWS / 128, TOTAL_OUT / 128), 256, 0, stream>>>(X1, W1T, Ub, VTg, Qb, Kb);
    attn_kernel<<<dim3(16, Hc, Bc), 256, 0, stream>>>(Qb, Kb, VTg, BIAS, Ob);
    ln2_kernel<<<ROWS / 4, 256, 0, stream>>>(Ob, Ub, ln2_g, ln2_b, A2);
    gemm2_kernel<<<dim3(ROWS / 128, Dc / 128), 256, 0, stream>>>(A2, W2T, out_b, x, outp);
}

// Round 10
// 246.410 us; speedup vs baseline: 1.1148x; 1.1148x over previous
//
#include <hip/hip_runtime.h>
#include <math.h>

// Problem constants
constexpr int Bc = 8;
constexpr int Lc = 1024;
constexpr int Dc = 512;        // model dim
constexpr int Hc = 8;
constexpr int DHc = 64;
constexpr int DLc = 64;
constexpr int NBc = 128;
constexpr int TOTAL_OUT = 2 * DLc * Hc + 2 * DHc * Hc;  // 2048
constexpr int ROWS = Bc * Lc;  // 8192

using f32x4 = __attribute__((ext_vector_type(4))) float;
using s16x8 = __attribute__((ext_vector_type(8))) short;

__device__ __forceinline__ float bf2f(ushort u) {
    union { unsigned int i; float f; } v; v.i = ((unsigned int)u) << 16; return v.f;
}
__device__ __forceinline__ ushort f2bf(float f) {
    union { float f; unsigned int i; } v; v.f = f;
    unsigned int r = v.i + 0x7fffu + ((v.i >> 16) & 1u);  // RNE
    return (ushort)(r >> 16);
}
// packed f32x2 -> bf16x2 (RNE), gfx950 native
__device__ __forceinline__ unsigned int cvtpk_bf16(float lo, float hi) {
    unsigned int r;
    asm("v_cvt_pk_bf16_f32 %0, %1, %2" : "=v"(r) : "v"(lo), "v"(hi));
    return r;
}
// silu via v_exp + v_rcp (1-instr transcendentals) instead of precise divide
__device__ __forceinline__ float silu(float x) {
    float e = __expf(-x);
    return x * __builtin_amdgcn_rcpf(1.0f + e);
}

// ---------------------------------------------------------------------------
// Transpose + cast fp32 (R x C) -> bf16 (C x R)
// ---------------------------------------------------------------------------
__global__ __launch_bounds__(256) void transpose_cast(const float* __restrict__ in,
                                                      ushort* __restrict__ out,
                                                      int R, int C) {
    __shared__ float tile[32][33];
    int bc = blockIdx.x * 32, br = blockIdx.y * 32;
    int tx = threadIdx.x & 31, ty = threadIdx.x >> 5;  // 32x8
    for (int i = ty; i < 32; i += 8) {
        int r = br + i, c = bc + tx;
        tile[i][tx] = (r < R && c < C) ? in[(size_t)r * C + c] : 0.f;
    }
    __syncthreads();
    for (int i = ty; i < 32; i += 8) {
        int c = bc + i, r = br + tx;
        if (c < C && r < R) out[(size_t)c * R + r] = f2bf(tile[tx][i]);
    }
}

// ---------------------------------------------------------------------------
// LN1: x (ROWS x 512 fp32) -> bf16 normalized. One wave per row.
// ---------------------------------------------------------------------------
__global__ __launch_bounds__(256) void ln1_kernel(const float* __restrict__ x,
                                                  const float* __restrict__ g,
                                                  const float* __restrict__ bta,
                                                  ushort* __restrict__ outp) {
    int wid = threadIdx.x >> 6, lane = threadIdx.x & 63;
    int row = blockIdx.x * 4 + wid;
    const float4* xr = (const float4*)(x + (size_t)row * Dc);
    float4 a = xr[lane * 2], c = xr[lane * 2 + 1];
    float xv[8] = {a.x, a.y, a.z, a.w, c.x, c.y, c.z, c.w};
    float s = 0.f, q = 0.f;
#pragma unroll
    for (int i = 0; i < 8; i++) { s += xv[i]; q += xv[i] * xv[i]; }
#pragma unroll
    for (int off = 32; off; off >>= 1) { s += __shfl_xor(s, off); q += __shfl_xor(q, off); }
    float mean = s * (1.f / 512.f);
    float var  = q * (1.f / 512.f) - mean * mean;
    float rstd = rsqrtf(var + 1e-6f);
    const float4* gv = (const float4*)g; const float4* bv = (const float4*)bta;
    float4 g0 = gv[lane * 2], g1 = gv[lane * 2 + 1];
    float4 b0 = bv[lane * 2], b1 = bv[lane * 2 + 1];
    float G[8] = {g0.x, g0.y, g0.z, g0.w, g1.x, g1.y, g1.z, g1.w};
    float Bv[8] = {b0.x, b0.y, b0.z, b0.w, b1.x, b1.y, b1.z, b1.w};
    union { ushort u16[8]; uint4 v; } pk;
#pragma unroll
    for (int i = 0; i < 8; i++) pk.u16[i] = f2bf((xv[i] - mean) * rstd * G[i] + Bv[i]);
    ((uint4*)(outp + (size_t)row * Dc))[lane] = pk.v;
}

// ---------------------------------------------------------------------------
// Bias precompute: bias[b][m][n] = pos_w[L-1+n-m] + ts_w[bucket(ts[m+1]-ts[n])]
// ---------------------------------------------------------------------------
__global__ __launch_bounds__(256) void bias_kernel(const int* __restrict__ ts,
                                                   const float* __restrict__ pos_w,
                                                   const float* __restrict__ ts_w,
                                                   ushort* __restrict__ biasb) {
    __shared__ float posw[2 * Lc - 1];
    __shared__ float tsw[NBc + 1];
    int tid = threadIdx.x;
    int b = blockIdx.y;
    for (int i = tid; i < 2 * Lc - 1; i += 256) posw[i] = pos_w[i];
    if (tid < NBc + 1) tsw[tid] = ts_w[tid];
    __syncthreads();
    int m = blockIdx.x * 8 + (tid >> 5);
    int n0 = (tid & 31) * 32;
    const int* tsb = ts + b * Lc;
    int mp = m + 1 < Lc ? m + 1 : Lc - 1;
    int tsm = tsb[mp];
    int pbase = (Lc - 1) + n0 - m;
    union { ushort u16[32]; uint4 v[4]; } o;
#pragma unroll
    for (int i = 0; i < 32; i += 4) {
        int4 tn = *(const int4*)&tsb[n0 + i];
        int dv[4] = {tsm - tn.x, tsm - tn.y, tsm - tn.z, tsm - tn.w};
#pragma unroll
        for (int e = 0; e < 4; e++) {
            float mag = fmaxf(fabsf((float)dv[e]), 1.f);
            int bkt = (int)(__log2f(mag) * 2.3028147f);  // ln(mag)/0.301
            bkt = bkt < 0 ? 0 : (bkt > NBc ? NBc : bkt);
            o.u16[i + e] = f2bf(posw[pbase + i + e] + tsw[bkt]);
        }
    }
    uint4* dst = (uint4*)&biasb[((size_t)b * Lc + m) * Lc + n0];
#pragma unroll
    for (int i = 0; i < 4; i++) dst[i] = o.v[i];
}

// ---------------------------------------------------------------------------
// GEMM1: X1 (8192x512 bf16) @ W1T^T -> silu -> split-store:
//   u, q, k row-major (8192x512 each); V TRANSPOSED: VT[(b*8+h)*64+d][n] (64 heads)
// ---------------------------------------------------------------------------
__global__ __launch_bounds__(256) void gemm1_kernel(const ushort* __restrict__ A,
                                                    const ushort* __restrict__ Bt,
                                                    ushort* __restrict__ Ub,
                                                    ushort* __restrict__ VTg,
                                                    ushort* __restrict__ Qb,
                                                    ushort* __restrict__ Kb) {
    __shared__ __align__(16) ushort As[128][72];
    __shared__ __align__(16) ushort Bs[128][72];
    int tid = threadIdx.x;
    int m0 = blockIdx.x * 128, n0 = blockIdx.y * 128;
    int w = tid >> 6, lane = tid & 63;
    int wm = (w >> 1) * 64, wn = (w & 1) * 64;
    f32x4 acc[4][4] = {};
    for (int k0 = 0; k0 < Dc; k0 += 64) {
        __syncthreads();
#pragma unroll
        for (int c = tid; c < 1024; c += 256) {
            int r = c >> 3, c8 = c & 7;
            *(uint4*)&As[r][c8 * 8] = *(const uint4*)&A[(size_t)(m0 + r) * Dc + k0 + c8 * 8];
            *(uint4*)&Bs[r][c8 * 8] = *(const uint4*)&Bt[(size_t)(n0 + r) * Dc + k0 + c8 * 8];
        }
        __syncthreads();
#pragma unroll
        for (int ks = 0; ks < 2; ++ks) {
            int kb = ks * 32 + (lane >> 4) * 8;
            s16x8 af[4], bfr[4];
#pragma unroll
            for (int i = 0; i < 4; i++) af[i] = *(const s16x8*)&As[wm + i * 16 + (lane & 15)][kb];
#pragma unroll
            for (int j = 0; j < 4; j++) bfr[j] = *(const s16x8*)&Bs[wn + j * 16 + (lane & 15)][kb];
#pragma unroll
            for (int i = 0; i < 4; i++)
#pragma unroll
                for (int j = 0; j < 4; j++)
                    acc[i][j] = __builtin_amdgcn_mfma_f32_16x16x32_bf16(af[i], bfr[j], acc[i][j], 0, 0, 0);
        }
    }
    int lr = (lane >> 4) * 4, lc = lane & 15;
#pragma unroll
    for (int i = 0; i < 4; i++)
#pragma unroll
        for (int j = 0; j < 4; j++) {
            int col = n0 + wn + j * 16 + lc;
            int sect = col >> 9, cc = col & 511;
            int row0 = m0 + wm + i * 16 + lr;
            if (sect == 1) {
                // V: transposed store. rows row0..row0+3 -> n consecutive
                int hh = cc >> 6, dd = cc & 63;
                int bb = row0 >> 10, nn = row0 & 1023;
                ushort4 pk;
                pk.x = f2bf(silu(acc[i][j][0]));
                pk.y = f2bf(silu(acc[i][j][1]));
                pk.z = f2bf(silu(acc[i][j][2]));
                pk.w = f2bf(silu(acc[i][j][3]));
                *(ushort4*)&VTg[((size_t)((bb * 8 + hh) * 64 + dd)) * 1024 + nn] = pk;
            } else {
                ushort* dst = (sect == 0) ? Ub : (sect == 2) ? Qb : Kb;
#pragma unroll
                for (int r = 0; r < 4; r++)
                    dst[(size_t)(row0 + r) * 512 + cc] = f2bf(silu(acc[i][j][r]));
            }
        }
}

// ---------------------------------------------------------------------------
// Fused causal attention, pipelined, swapped-QK^T layout.
// Grid (16, H, B): 64 M-rows/block, 4 waves x 16 rows.
// mt map is co-residency-aware: blocks sharing a CU (b stepping by 2) get
// complementary work. S computed as K*Q^T so each lane owns one m-row with
// consecutive n -> bias loads vectorize (ushort4) and P packs via cvt_pk.
// ---------------------------------------------------------------------------
__global__ __launch_bounds__(256) void attn_kernel(const ushort* __restrict__ Qb,
                                                   const ushort* __restrict__ Kb,
                                                   const ushort* __restrict__ VTg,
                                                   const ushort* __restrict__ biasb,
                                                   ushort* __restrict__ Ob) {
    int bx = blockIdx.x;
    int h = blockIdx.y, b = blockIdx.z;
    // co-resident blocks: same bx,h; b differs by 2 -> s=(b>>1) spans 0..3
    int pidx = (bx + ((b >> 1) & 3)) & 15;
    int mt = (pidx & 1) ? (pidx >> 1) : (15 - (pidx >> 1));
    __shared__ __align__(16) ushort Ks[2][64][64];   // 16 KB, XOR-swizzled slots
    __shared__ __align__(16) ushort Ps[4][16][64];   // 8 KB, wave-private, swizzled
    int tid = threadIdx.x, w = tid >> 6, lane = tid & 63;
    const size_t qkbase = ((size_t)b * Lc) * 512 + h * 64;
    const size_t vtbase = ((size_t)((b * 8 + h) * 64)) * 1024;
    const ushort* biasB = biasb + (size_t)b * Lc * Lc;
    const int m0 = mt * 64;
    int lc = lane & 15, g4 = lane >> 4;
    // --- K staging geometry: thread t covers 32B of the 8KB tile ---
    int sr = tid >> 2;               // tile row 0..63
    int ss0 = (tid & 3) * 2;         // 16B-slot 0,2,4,6
    const ushort* kgrow = Kb + qkbase + (size_t)sr * 512;
    int dso0 = sr * 64 + (((ss0)     ^ (sr & 7)) * 8);
    int dso1 = sr * 64 + (((ss0 + 1) ^ (sr & 7)) * 8);

    // prologue: stage K(0) into Ks[0]
    {
        uint4 ka = *(const uint4*)(kgrow + ss0 * 8);
        uint4 kb_ = *(const uint4*)(kgrow + (ss0 + 1) * 8);
        *(uint4*)&(&Ks[0][0][0])[dso0] = ka;
        *(uint4*)&(&Ks[0][0][0])[dso1] = kb_;
    }
    __syncthreads();

    // Q fragments (B-operand for swapped QK): lane's m-row = m0 + w*16 + lc
    const int mrow_in64 = w * 16 + lc;       // m within the 64-row block
    const int mrow = m0 + mrow_in64;         // absolute m (this lane's row)
    s16x8 qf[2];
#pragma unroll
    for (int ks = 0; ks < 2; ++ks)
        qf[ks] = *(const s16x8*)&Qb[qkbase + (size_t)mrow * 512 + ks * 32 + g4 * 8];

    ushort* psW = &Ps[w][0][0];
    f32x4 acc_o[4] = {};
    int ntiles = mt + 1;
    int cur = 0;
    for (int nt = 0; nt < ntiles; ++nt) {
        int n0 = nt * 64;
        // prefetch V^T fragments for THIS tile (consumed at bottom)
        s16x8 vb[2][4];
#pragma unroll
        for (int ks = 0; ks < 2; ++ks)
#pragma unroll
            for (int j = 0; j < 4; j++)
                vb[ks][j] = *(const s16x8*)&VTg[vtbase + (size_t)(j * 16 + lc) * 1024 + n0 + ks * 32 + g4 * 8];
        // prefetch bias: lane's m-row, 4 consecutive n per j -> ushort4
        ushort4 bsv[4];
#pragma unroll
        for (int j = 0; j < 4; j++)
            bsv[j] = *(const ushort4*)&biasB[(size_t)mrow * Lc + n0 + j * 16 + g4 * 4];
        // prefetch K(nt+1) into regs (ds_write after PV)
        bool hasnext = (nt + 1 < ntiles);
        uint4 ka = {}, kb_ = {};
        if (hasnext) {
            const ushort* kgn = kgrow + (size_t)(n0 + 64) * 512;
            ka  = *(const uint4*)(kgn + ss0 * 8);
            kb_ = *(const uint4*)(kgn + (ss0 + 1) * 8);
        }
        // S^T = K Q^T from swizzled LDS: s[j][r] = S[m=lc-row][n = n0+j*16+g4*4+r]
        const ushort* ksb = &Ks[cur][0][0];
        f32x4 s[4] = {};
#pragma unroll
        for (int ks = 0; ks < 2; ++ks) {
            s16x8 kf[4];
#pragma unroll
            for (int j = 0; j < 4; j++)
                kf[j] = *(const s16x8*)&ksb[(j * 16 + lc) * 64 + (((ks * 4 + g4) ^ (lc & 7)) * 8)];
#pragma unroll
            for (int j = 0; j < 4; j++)
                s[j] = __builtin_amdgcn_mfma_f32_16x16x32_bf16(kf[j], qf[ks], s[j], 0, 0, 0);
        }
        // bias + silu + mask -> pack bf16 pairs -> wave-private swizzled Ps
        bool diag = (nt == mt);
        const ushort* bp;
#pragma unroll
        for (int j = 0; j < 4; j++) {
            float p[4];
            bp = (const ushort*)&bsv[j];
#pragma unroll
            for (int r = 0; r < 4; r++) {
                float sv = s[j][r] + bf2f(bp[r]);
                float val = silu(sv) * (1.f / (float)Lc);
                if (diag && (j * 16 + g4 * 4 + r) > mrow_in64) val = 0.f;
                p[r] = val;
            }
            unsigned int w0 = cvtpk_bf16(p[0], p[1]);
            unsigned int w1 = cvtpk_bf16(p[2], p[3]);
            int slot16 = j * 2 + (g4 >> 1);
            int off = lc * 64 + ((slot16 ^ (lc & 7)) * 8) + (g4 & 1) * 4;  // ushort units
            *(uint2*)&psW[off] = make_uint2(w0, w1);
        }
        // O += P V  (A-frag: lane's m-row, 8 consecutive n from swizzled Ps)
#pragma unroll
        for (int ks = 0; ks < 2; ++ks) {
            int rs = ks * 4 + g4;
            s16x8 pa = *(const s16x8*)&psW[lc * 64 + ((rs ^ (lc & 7)) * 8)];
#pragma unroll
            for (int j = 0; j < 4; j++)
                acc_o[j] = __builtin_amdgcn_mfma_f32_16x16x32_bf16(pa, vb[ks][j], acc_o[j], 0, 0, 0);
        }
        // stage K(nt+1) into the other buffer
        if (hasnext) {
            ushort* kd = &Ks[cur ^ 1][0][0];
            *(uint4*)&kd[dso0] = ka;
            *(uint4*)&kd[dso1] = kb_;
        }
        __syncthreads();
        cur ^= 1;
    }
    // epilogue: acc_o[j][r] = O[m = m0 + w*16 + g4*4 + r][d = j*16 + lc]
    int mbase = m0 + w * 16 + g4 * 4;
#pragma unroll
    for (int j = 0; j < 4; j++)
#pragma unroll
        for (int r = 0; r < 4; r++) {
            int m = mbase + r;
            Ob[qkbase + (size_t)m * 512 + j * 16 + lc] = f2bf(acc_o[j][r]);
        }
}

// ---------------------------------------------------------------------------
// LN2(attn) * u -> bf16. One wave per row.
// ---------------------------------------------------------------------------
__global__ __launch_bounds__(256) void ln2_kernel(const ushort* __restrict__ z,
                                                  const ushort* __restrict__ u,
                                                  const float* __restrict__ g,
                                                  const float* __restrict__ bta,
                                                  ushort* __restrict__ outp) {
    int wid = threadIdx.x >> 6, lane = threadIdx.x & 63;
    int row = blockIdx.x * 4 + wid;
    uint4 zv = ((const uint4*)(z + (size_t)row * 512))[lane];
    ushort* zu = (ushort*)&zv;
    float xv[8], s = 0.f, q = 0.f;
#pragma unroll
    for (int i = 0; i < 8; i++) { xv[i] = bf2f(zu[i]); s += xv[i]; q += xv[i] * xv[i]; }
#pragma unroll
    for (int off = 32; off; off >>= 1) { s += __shfl_xor(s, off); q += __shfl_xor(q, off); }
    float mean = s * (1.f / 512.f);
    float var  = q * (1.f / 512.f) - mean * mean;
    float rstd = rsqrtf(var + 1e-6f);
    uint4 uv = ((const uint4*)(u + (size_t)row * 512))[lane];
    ushort* uu = (ushort*)&uv;
    const float4* gv = (const float4*)g; const float4* bv = (const float4*)bta;
    float4 g0 = gv[lane * 2], g1 = gv[lane * 2 + 1];
    float4 b0 = bv[lane * 2], b1 = bv[lane * 2 + 1];
    float G[8] = {g0.x, g0.y, g0.z, g0.w, g1.x, g1.y, g1.z, g1.w};
    float Bv[8] = {b0.x, b0.y, b0.z, b0.w, b1.x, b1.y, b1.z, b1.w};
    union { ushort u16[8]; uint4 v; } pk;
#pragma unroll
    for (int i = 0; i < 8; i++)
        pk.u16[i] = f2bf(((xv[i] - mean) * rstd * G[i] + Bv[i]) * bf2f(uu[i]));
    ((uint4*)(outp + (size_t)row * 512))[lane] = pk.v;
}

// ---------------------------------------------------------------------------
// GEMM2: A2 (8192x512 bf16) @ W2T^T + out_b + x -> fp32
// ---------------------------------------------------------------------------
__global__ __launch_bounds__(256) void gemm2_kernel(const ushort* __restrict__ A,
                                                    const ushort* __restrict__ Bt,
                                                    const float* __restrict__ ob,
                                                    const float* __restrict__ x,
                                                    float* __restrict__ outp) {
    __shared__ __align__(16) ushort As[128][72];
    __shared__ __align__(16) ushort Bs[128][72];
    int tid = threadIdx.x;
    int m0 = blockIdx.x * 128, n0 = blockIdx.y * 128;
    int w = tid >> 6, lane = tid & 63;
    int wm = (w >> 1) * 64, wn = (w & 1) * 64;
    f32x4 acc[4][4] = {};
    for (int k0 = 0; k0 < Dc; k0 += 64) {
        __syncthreads();
#pragma unroll
        for (int c = tid; c < 1024; c += 256) {
            int r = c >> 3, c8 = c & 7;
            *(uint4*)&As[r][c8 * 8] = *(const uint4*)&A[(size_t)(m0 + r) * Dc + k0 + c8 * 8];
            *(uint4*)&Bs[r][c8 * 8] = *(const uint4*)&Bt[(size_t)(n0 + r) * Dc + k0 + c8 * 8];
        }
        __syncthreads();
#pragma unroll
        for (int ks = 0; ks < 2; ++ks) {
            int kb = ks * 32 + (lane >> 4) * 8;
            s16x8 af[4], bfr[4];
#pragma unroll
            for (int i = 0; i < 4; i++) af[i] = *(const s16x8*)&As[wm + i * 16 + (lane & 15)][kb];
#pragma unroll
            for (int j = 0; j < 4; j++) bfr[j] = *(const s16x8*)&Bs[wn + j * 16 + (lane & 15)][kb];
#pragma unroll
            for (int i = 0; i < 4; i++)
#pragma unroll
                for (int j = 0; j < 4; j++)
                    acc[i][j] = __builtin_amdgcn_mfma_f32_16x16x32_bf16(af[i], bfr[j], acc[i][j], 0, 0, 0);
        }
    }
    int lr = (lane >> 4) * 4, lc = lane & 15;
#pragma unroll
    for (int i = 0; i < 4; i++)
#pragma unroll
        for (int j = 0; j < 4; j++) {
            int col = n0 + wn + j * 16 + lc;
            float bias = ob[col];
#pragma unroll
            for (int r = 0; r < 4; r++) {
                int row = m0 + wm + i * 16 + lr + r;
                size_t off = (size_t)row * 512 + col;
                outp[off] = acc[i][j][r] + bias + x[off];
            }
        }
}

// ---------------------------------------------------------------------------
extern "C" void kernel_launch(void* const* d_in, const int* in_sizes, int n_in,
                              void* d_out, int out_size, void* d_ws, size_t ws_size,
                              hipStream_t stream) {
    const float* x      = (const float*)d_in[0];
    const int*   tsp    = (const int*)d_in[1];
    // d_in[2]: attn_mask (implicit causal; unused)
    const float* uvqk_w = (const float*)d_in[3];
    const float* out_w  = (const float*)d_in[4];
    const float* out_b  = (const float*)d_in[5];
    const float* ln1_g  = (const float*)d_in[6];
    const float* ln1_b  = (const float*)d_in[7];
    const float* ln2_g  = (const float*)d_in[8];
    const float* ln2_b  = (const float*)d_in[9];
    const float* ts_w   = (const float*)d_in[10];
    const float* pos_w  = (const float*)d_in[11];
    float* outp = (float*)d_out;

    char* ws = (char*)d_ws;
    size_t off = 0;
    auto alloc = [&](size_t bytes) { char* p = ws + off; off += (bytes + 255) & ~(size_t)255; return p; };
    const size_t MAT = (size_t)ROWS * 512 * sizeof(ushort);  // 8 MB
    ushort* W1T = (ushort*)alloc((size_t)TOTAL_OUT * Dc * 2);  // 2 MB
    ushort* W2T = (ushort*)alloc((size_t)Dc * Dc * 2);         // 0.5 MB
    ushort* X1  = (ushort*)alloc(MAT);
    ushort* Ub  = (ushort*)alloc(MAT);
    ushort* VTg = (ushort*)alloc(MAT);  // V transposed: [(b*8+h)*64+d][n]
    ushort* Qb  = (ushort*)alloc(MAT);
    ushort* Kb  = (ushort*)alloc(MAT);
    ushort* Ob  = (ushort*)alloc(MAT);
    ushort* BIAS = (ushort*)alloc((size_t)Bc * Lc * Lc * 2);  // 16.8 MB
    ushort* A2  = X1;  // X1 dead after gemm1 -> reuse for ln2 output

    transpose_cast<<<dim3(TOTAL_OUT / 32, Dc / 32), 256, 0, stream>>>(uvqk_w, W1T, Dc, TOTAL_OUT);
    transpose_cast<<<dim3(Dc / 32, Dc / 32), 256, 0, stream>>>(out_w, W2T, Dc, Dc);
    bias_kernel<<<dim3(Lc / 8, Bc), 256, 0, stream>>>(tsp, pos_w, ts_w, BIAS);
    ln1_kernel<<<ROWS / 4, 256, 0, stream>>>(x, ln1_g, ln1_b, X1);
    gemm1_kernel<<<dim3(ROWS / 128, TOTAL_OUT / 128), 256, 0, stream>>>(X1, W1T, Ub, VTg, Qb, Kb);
    attn_kernel<<<dim3(16, Hc, Bc), 256, 0, stream>>>(Qb, Kb, VTg, BIAS, Ob);
    ln2_kernel<<<ROWS / 4, 256, 0, stream>>>(Ob, Ub, ln2_g, ln2_b, A2);
    gemm2_kernel<<<dim3(ROWS / 128, Dc / 128), 256, 0, stream>>>(A2, W2T, out_b, x, outp);
}

// Round 11
// 245.847 us; speedup vs baseline: 1.1174x; 1.0023x over previous
//
#include <hip/hip_runtime.h>
#include <math.h>

// Problem constants
constexpr int Bc = 8;
constexpr int Lc = 1024;
constexpr int Dc = 512;        // model dim
constexpr int Hc = 8;
constexpr int DHc = 64;
constexpr int DLc = 64;
constexpr int NBc = 128;
constexpr int TOTAL_OUT = 2 * DLc * Hc + 2 * DHc * Hc;  // 2048
constexpr int ROWS = Bc * Lc;  // 8192

using f32x4 = __attribute__((ext_vector_type(4))) float;
using s16x8 = __attribute__((ext_vector_type(8))) short;

__device__ __forceinline__ float bf2f(ushort u) {
    union { unsigned int i; float f; } v; v.i = ((unsigned int)u) << 16; return v.f;
}
__device__ __forceinline__ ushort f2bf(float f) {
    union { float f; unsigned int i; } v; v.f = f;
    unsigned int r = v.i + 0x7fffu + ((v.i >> 16) & 1u);  // RNE
    return (ushort)(r >> 16);
}
// packed f32x2 -> bf16x2 (RNE), gfx950 native
__device__ __forceinline__ unsigned int cvtpk_bf16(float lo, float hi) {
    unsigned int r;
    asm("v_cvt_pk_bf16_f32 %0, %1, %2" : "=v"(r) : "v"(lo), "v"(hi));
    return r;
}
// silu via v_exp + v_rcp (1-instr transcendentals) instead of precise divide
__device__ __forceinline__ float silu(float x) {
    float e = __expf(-x);
    return x * __builtin_amdgcn_rcpf(1.0f + e);
}

// ---------------------------------------------------------------------------
// Transpose + cast fp32 (R x C) -> bf16 (C x R)
// ---------------------------------------------------------------------------
__global__ __launch_bounds__(256) void transpose_cast(const float* __restrict__ in,
                                                      ushort* __restrict__ out,
                                                      int R, int C) {
    __shared__ float tile[32][33];
    int bc = blockIdx.x * 32, br = blockIdx.y * 32;
    int tx = threadIdx.x & 31, ty = threadIdx.x >> 5;  // 32x8
    for (int i = ty; i < 32; i += 8) {
        int r = br + i, c = bc + tx;
        tile[i][tx] = (r < R && c < C) ? in[(size_t)r * C + c] : 0.f;
    }
    __syncthreads();
    for (int i = ty; i < 32; i += 8) {
        int c = bc + i, r = br + tx;
        if (c < C && r < R) out[(size_t)c * R + r] = f2bf(tile[tx][i]);
    }
}

// ---------------------------------------------------------------------------
// LN1: x (ROWS x 512 fp32) -> bf16 normalized. One wave per row.
// ---------------------------------------------------------------------------
__global__ __launch_bounds__(256) void ln1_kernel(const float* __restrict__ x,
                                                  const float* __restrict__ g,
                                                  const float* __restrict__ bta,
                                                  ushort* __restrict__ outp) {
    int wid = threadIdx.x >> 6, lane = threadIdx.x & 63;
    int row = blockIdx.x * 4 + wid;
    const float4* xr = (const float4*)(x + (size_t)row * Dc);
    float4 a = xr[lane * 2], c = xr[lane * 2 + 1];
    float xv[8] = {a.x, a.y, a.z, a.w, c.x, c.y, c.z, c.w};
    float s = 0.f, q = 0.f;
#pragma unroll
    for (int i = 0; i < 8; i++) { s += xv[i]; q += xv[i] * xv[i]; }
#pragma unroll
    for (int off = 32; off; off >>= 1) { s += __shfl_xor(s, off); q += __shfl_xor(q, off); }
    float mean = s * (1.f / 512.f);
    float var  = q * (1.f / 512.f) - mean * mean;
    float rstd = rsqrtf(var + 1e-6f);
    const float4* gv = (const float4*)g; const float4* bv = (const float4*)bta;
    float4 g0 = gv[lane * 2], g1 = gv[lane * 2 + 1];
    float4 b0 = bv[lane * 2], b1 = bv[lane * 2 + 1];
    float G[8] = {g0.x, g0.y, g0.z, g0.w, g1.x, g1.y, g1.z, g1.w};
    float Bv[8] = {b0.x, b0.y, b0.z, b0.w, b1.x, b1.y, b1.z, b1.w};
    union { ushort u16[8]; uint4 v; } pk;
#pragma unroll
    for (int i = 0; i < 8; i++) pk.u16[i] = f2bf((xv[i] - mean) * rstd * G[i] + Bv[i]);
    ((uint4*)(outp + (size_t)row * Dc))[lane] = pk.v;
}

// ---------------------------------------------------------------------------
// Bias precompute: bias[b][m][n] = pos_w[L-1+n-m] + ts_w[bucket(ts[m+1]-ts[n])]
// ---------------------------------------------------------------------------
__global__ __launch_bounds__(256) void bias_kernel(const int* __restrict__ ts,
                                                   const float* __restrict__ pos_w,
                                                   const float* __restrict__ ts_w,
                                                   ushort* __restrict__ biasb) {
    __shared__ float posw[2 * Lc - 1];
    __shared__ float tsw[NBc + 1];
    int tid = threadIdx.x;
    int b = blockIdx.y;
    for (int i = tid; i < 2 * Lc - 1; i += 256) posw[i] = pos_w[i];
    if (tid < NBc + 1) tsw[tid] = ts_w[tid];
    __syncthreads();
    int m = blockIdx.x * 8 + (tid >> 5);
    int n0 = (tid & 31) * 32;
    const int* tsb = ts + b * Lc;
    int mp = m + 1 < Lc ? m + 1 : Lc - 1;
    int tsm = tsb[mp];
    int pbase = (Lc - 1) + n0 - m;
    union { ushort u16[32]; uint4 v[4]; } o;
#pragma unroll
    for (int i = 0; i < 32; i += 4) {
        int4 tn = *(const int4*)&tsb[n0 + i];
        int dv[4] = {tsm - tn.x, tsm - tn.y, tsm - tn.z, tsm - tn.w};
#pragma unroll
        for (int e = 0; e < 4; e++) {
            float mag = fmaxf(fabsf((float)dv[e]), 1.f);
            int bkt = (int)(__log2f(mag) * 2.3028147f);  // ln(mag)/0.301
            bkt = bkt < 0 ? 0 : (bkt > NBc ? NBc : bkt);
            o.u16[i + e] = f2bf(posw[pbase + i + e] + tsw[bkt]);
        }
    }
    uint4* dst = (uint4*)&biasb[((size_t)b * Lc + m) * Lc + n0];
#pragma unroll
    for (int i = 0; i < 4; i++) dst[i] = o.v[i];
}

// ---------------------------------------------------------------------------
// GEMM1: X1 @ W1T^T -> silu -> split-store. OPERAND-SWAPPED mfma: output reg
// dim = column -> vectorized ushort4 stores for u/q/k. V stored transposed
// VT[(b*8+h)*64+d][n] (scalar stores, 1/4 of output).
// ---------------------------------------------------------------------------
__global__ __launch_bounds__(256) void gemm1_kernel(const ushort* __restrict__ A,
                                                    const ushort* __restrict__ Bt,
                                                    ushort* __restrict__ Ub,
                                                    ushort* __restrict__ VTg,
                                                    ushort* __restrict__ Qb,
                                                    ushort* __restrict__ Kb) {
    __shared__ __align__(16) ushort As[128][72];
    __shared__ __align__(16) ushort Bs[128][72];
    int tid = threadIdx.x;
    int m0 = blockIdx.x * 128, n0 = blockIdx.y * 128;
    int w = tid >> 6, lane = tid & 63;
    int wm = (w >> 1) * 64, wn = (w & 1) * 64;
    f32x4 acc[4][4] = {};
    for (int k0 = 0; k0 < Dc; k0 += 64) {
        __syncthreads();
#pragma unroll
        for (int c = tid; c < 1024; c += 256) {
            int r = c >> 3, c8 = c & 7;
            *(uint4*)&As[r][c8 * 8] = *(const uint4*)&A[(size_t)(m0 + r) * Dc + k0 + c8 * 8];
            *(uint4*)&Bs[r][c8 * 8] = *(const uint4*)&Bt[(size_t)(n0 + r) * Dc + k0 + c8 * 8];
        }
        __syncthreads();
#pragma unroll
        for (int ks = 0; ks < 2; ++ks) {
            int kb = ks * 32 + (lane >> 4) * 8;
            s16x8 af[4], bfr[4];
#pragma unroll
            for (int i = 0; i < 4; i++) af[i] = *(const s16x8*)&As[wm + i * 16 + (lane & 15)][kb];
#pragma unroll
            for (int j = 0; j < 4; j++) bfr[j] = *(const s16x8*)&Bs[wn + j * 16 + (lane & 15)][kb];
#pragma unroll
            for (int i = 0; i < 4; i++)
#pragma unroll
                for (int j = 0; j < 4; j++)
                    acc[i][j] = __builtin_amdgcn_mfma_f32_16x16x32_bf16(bfr[j], af[i], acc[i][j], 0, 0, 0);
        }
    }
    // swapped layout: per-lane m fixed (lane&15), reg r = consecutive n
    int lr = (lane >> 4) * 4, lc = lane & 15;
#pragma unroll
    for (int i = 0; i < 4; i++) {
        int m = m0 + wm + i * 16 + lc;
#pragma unroll
        for (int j = 0; j < 4; j++) {
            int col0 = n0 + wn + j * 16 + lr;
            int sect = col0 >> 9, cc0 = col0 & 511;
            if (sect == 1) {
                // V: VT[d][n]; d = cc0..cc0+3 (stride 1024), n = m
                int hh = cc0 >> 6, dd0 = cc0 & 63;
                int bb = m >> 10, nn = m & 1023;
                size_t base = ((size_t)((bb * 8 + hh) * 64 + dd0)) * 1024 + nn;
#pragma unroll
                for (int r = 0; r < 4; r++)
                    VTg[base + (size_t)r * 1024] = f2bf(silu(acc[i][j][r]));
            } else {
                ushort* dst = (sect == 0) ? Ub : (sect == 2) ? Qb : Kb;
                ushort4 pk;
                pk.x = f2bf(silu(acc[i][j][0]));
                pk.y = f2bf(silu(acc[i][j][1]));
                pk.z = f2bf(silu(acc[i][j][2]));
                pk.w = f2bf(silu(acc[i][j][3]));
                *(ushort4*)&dst[(size_t)m * 512 + cc0] = pk;
            }
        }
    }
}

// ---------------------------------------------------------------------------
// Fused causal attention: paired-tile uniform blocks.
// Grid (8, H, B): block i handles M-tiles {i, 15-i}; every block = exactly 17
// tile-computations -> all 512 blocks co-resident, start & finish together.
// K staged once (dbuf LDS, XOR-swizzled) serves both tiles; V^T and bias
// prefetched from global. Swapped-QK^T layout (lane owns one m-row).
// ---------------------------------------------------------------------------
__global__ __launch_bounds__(256) void attn_kernel(const ushort* __restrict__ Qb,
                                                   const ushort* __restrict__ Kb,
                                                   const ushort* __restrict__ VTg,
                                                   const ushort* __restrict__ biasb,
                                                   ushort* __restrict__ Ob) {
    int iA = blockIdx.x;       // 0..7
    int iB = 15 - iA;          // 8..15
    int h = blockIdx.y, b = blockIdx.z;
    __shared__ __align__(16) ushort Ks[2][64][64];      // 16 KB, XOR-swizzled
    __shared__ __align__(16) ushort Ps[4][2][16][64];   // 16 KB, wave-private
    int tid = threadIdx.x, w = tid >> 6, lane = tid & 63;
    const size_t qkbase = ((size_t)b * Lc) * 512 + h * 64;
    const size_t vtbase = ((size_t)((b * 8 + h) * 64)) * 1024;
    const ushort* biasT = biasb + (size_t)b * Lc * Lc;
    int lc = lane & 15, g4 = lane >> 4;
    // --- K staging geometry: thread t covers 32B of the 8KB tile ---
    int sr = tid >> 2;               // tile row 0..63
    int ss0 = (tid & 3) * 2;         // 16B-slot 0,2,4,6
    const ushort* kgrow = Kb + qkbase + (size_t)sr * 512;
    int dso0 = sr * 64 + (((ss0)     ^ (sr & 7)) * 8);
    int dso1 = sr * 64 + (((ss0 + 1) ^ (sr & 7)) * 8);

    // prologue: stage K(0) into Ks[0]
    {
        uint4 ka = *(const uint4*)(kgrow + ss0 * 8);
        uint4 kb_ = *(const uint4*)(kgrow + (ss0 + 1) * 8);
        *(uint4*)&(&Ks[0][0][0])[dso0] = ka;
        *(uint4*)&(&Ks[0][0][0])[dso1] = kb_;
    }
    __syncthreads();

    const int m0A = iA * 64, m0B = iB * 64;
    const int mloc = w * 16 + lc;          // lane's m within a 64-row tile
    const int mrowA = m0A + mloc, mrowB = m0B + mloc;
    s16x8 qfA[2], qfB[2];
#pragma unroll
    for (int ks = 0; ks < 2; ++ks) {
        qfA[ks] = *(const s16x8*)&Qb[qkbase + (size_t)mrowA * 512 + ks * 32 + g4 * 8];
        qfB[ks] = *(const s16x8*)&Qb[qkbase + (size_t)mrowB * 512 + ks * 32 + g4 * 8];
    }
    ushort* psA = &Ps[w][0][0][0];
    ushort* psB = &Ps[w][1][0][0];
    f32x4 accA[4] = {}, accB[4] = {};
    int cur = 0;
    for (int nt = 0; nt <= iB; ++nt) {
        int n0 = nt * 64;
        bool aact = (nt <= iA);
        // prefetch V^T fragments (shared by both tiles)
        s16x8 vb[2][4];
#pragma unroll
        for (int ks = 0; ks < 2; ++ks)
#pragma unroll
            for (int j = 0; j < 4; j++)
                vb[ks][j] = *(const s16x8*)&VTg[vtbase + (size_t)(j * 16 + lc) * 1024 + n0 + ks * 32 + g4 * 8];
        // prefetch bias rows
        ushort4 bsvB[4], bsvA[4];
#pragma unroll
        for (int j = 0; j < 4; j++)
            bsvB[j] = *(const ushort4*)&biasT[(size_t)mrowB * Lc + n0 + j * 16 + g4 * 4];
        if (aact) {
#pragma unroll
            for (int j = 0; j < 4; j++)
                bsvA[j] = *(const ushort4*)&biasT[(size_t)mrowA * Lc + n0 + j * 16 + g4 * 4];
        }
        // prefetch K(nt+1) into regs (ds_write after PV)
        bool hasnext = (nt < iB);
        uint4 ka = {}, kb_ = {};
        if (hasnext) {
            const ushort* kgn = kgrow + (size_t)(n0 + 64) * 512;
            ka  = *(const uint4*)(kgn + ss0 * 8);
            kb_ = *(const uint4*)(kgn + (ss0 + 1) * 8);
        }
        // S^T = K Q^T from swizzled LDS (both tiles share kf)
        const ushort* ksb = &Ks[cur][0][0];
        f32x4 sB[4] = {}, sA[4] = {};
#pragma unroll
        for (int ks = 0; ks < 2; ++ks) {
            s16x8 kf[4];
#pragma unroll
            for (int j = 0; j < 4; j++)
                kf[j] = *(const s16x8*)&ksb[(j * 16 + lc) * 64 + (((ks * 4 + g4) ^ (lc & 7)) * 8)];
#pragma unroll
            for (int j = 0; j < 4; j++) {
                sB[j] = __builtin_amdgcn_mfma_f32_16x16x32_bf16(kf[j], qfB[ks], sB[j], 0, 0, 0);
                if (aact)
                    sA[j] = __builtin_amdgcn_mfma_f32_16x16x32_bf16(kf[j], qfA[ks], sA[j], 0, 0, 0);
            }
        }
        // bias + silu + mask -> pack -> Ps (B stream)
        {
            bool diag = (nt == iB);
#pragma unroll
            for (int j = 0; j < 4; j++) {
                const ushort* bp = (const ushort*)&bsvB[j];
                float p[4];
#pragma unroll
                for (int r = 0; r < 4; r++) {
                    float sv = sB[j][r] + bf2f(bp[r]);
                    float val = silu(sv) * (1.f / (float)Lc);
                    if (diag && (j * 16 + g4 * 4 + r) > mloc) val = 0.f;
                    p[r] = val;
                }
                unsigned int w0 = cvtpk_bf16(p[0], p[1]);
                unsigned int w1 = cvtpk_bf16(p[2], p[3]);
                int slot16 = j * 2 + (g4 >> 1);
                int off = lc * 64 + ((slot16 ^ (lc & 7)) * 8) + (g4 & 1) * 4;
                *(uint2*)&psB[off] = make_uint2(w0, w1);
            }
        }
        if (aact) {
            bool diag = (nt == iA);
#pragma unroll
            for (int j = 0; j < 4; j++) {
                const ushort* bp = (const ushort*)&bsvA[j];
                float p[4];
#pragma unroll
                for (int r = 0; r < 4; r++) {
                    float sv = sA[j][r] + bf2f(bp[r]);
                    float val = silu(sv) * (1.f / (float)Lc);
                    if (diag && (j * 16 + g4 * 4 + r) > mloc) val = 0.f;
                    p[r] = val;
                }
                unsigned int w0 = cvtpk_bf16(p[0], p[1]);
                unsigned int w1 = cvtpk_bf16(p[2], p[3]);
                int slot16 = j * 2 + (g4 >> 1);
                int off = lc * 64 + ((slot16 ^ (lc & 7)) * 8) + (g4 & 1) * 4;
                *(uint2*)&psA[off] = make_uint2(w0, w1);
            }
        }
        // O += P V  (in-wave Ps ordering; vb shared)
#pragma unroll
        for (int ks = 0; ks < 2; ++ks) {
            int rs = ks * 4 + g4;
            s16x8 paB = *(const s16x8*)&psB[lc * 64 + ((rs ^ (lc & 7)) * 8)];
#pragma unroll
            for (int j = 0; j < 4; j++)
                accB[j] = __builtin_amdgcn_mfma_f32_16x16x32_bf16(paB, vb[ks][j], accB[j], 0, 0, 0);
            if (aact) {
                s16x8 paA = *(const s16x8*)&psA[lc * 64 + ((rs ^ (lc & 7)) * 8)];
#pragma unroll
                for (int j = 0; j < 4; j++)
                    accA[j] = __builtin_amdgcn_mfma_f32_16x16x32_bf16(paA, vb[ks][j], accA[j], 0, 0, 0);
            }
        }
        // stage K(nt+1) into the other buffer
        if (hasnext) {
            ushort* kd = &Ks[cur ^ 1][0][0];
            *(uint4*)&kd[dso0] = ka;
            *(uint4*)&kd[dso1] = kb_;
        }
        __syncthreads();
        cur ^= 1;
    }
    // epilogue: acc[j][r] = O[m = m0 + w*16 + g4*4 + r][d = j*16 + lc]
    int mbA = m0A + w * 16 + g4 * 4;
    int mbB = m0B + w * 16 + g4 * 4;
#pragma unroll
    for (int j = 0; j < 4; j++)
#pragma unroll
        for (int r = 0; r < 4; r++) {
            Ob[qkbase + (size_t)(mbA + r) * 512 + j * 16 + lc] = f2bf(accA[j][r]);
            Ob[qkbase + (size_t)(mbB + r) * 512 + j * 16 + lc] = f2bf(accB[j][r]);
        }
}

// ---------------------------------------------------------------------------
// LN2(attn) * u -> bf16. One wave per row.
// ---------------------------------------------------------------------------
__global__ __launch_bounds__(256) void ln2_kernel(const ushort* __restrict__ z,
                                                  const ushort* __restrict__ u,
                                                  const float* __restrict__ g,
                                                  const float* __restrict__ bta,
                                                  ushort* __restrict__ outp) {
    int wid = threadIdx.x >> 6, lane = threadIdx.x & 63;
    int row = blockIdx.x * 4 + wid;
    uint4 zv = ((const uint4*)(z + (size_t)row * 512))[lane];
    ushort* zu = (ushort*)&zv;
    float xv[8], s = 0.f, q = 0.f;
#pragma unroll
    for (int i = 0; i < 8; i++) { xv[i] = bf2f(zu[i]); s += xv[i]; q += xv[i] * xv[i]; }
#pragma unroll
    for (int off = 32; off; off >>= 1) { s += __shfl_xor(s, off); q += __shfl_xor(q, off); }
    float mean = s * (1.f / 512.f);
    float var  = q * (1.f / 512.f) - mean * mean;
    float rstd = rsqrtf(var + 1e-6f);
    uint4 uv = ((const uint4*)(u + (size_t)row * 512))[lane];
    ushort* uu = (ushort*)&uv;
    const float4* gv = (const float4*)g; const float4* bv = (const float4*)bta;
    float4 g0 = gv[lane * 2], g1 = gv[lane * 2 + 1];
    float4 b0 = bv[lane * 2], b1 = bv[lane * 2 + 1];
    float G[8] = {g0.x, g0.y, g0.z, g0.w, g1.x, g1.y, g1.z, g1.w};
    float Bv[8] = {b0.x, b0.y, b0.z, b0.w, b1.x, b1.y, b1.z, b1.w};
    union { ushort u16[8]; uint4 v; } pk;
#pragma unroll
    for (int i = 0; i < 8; i++)
        pk.u16[i] = f2bf(((xv[i] - mean) * rstd * G[i] + Bv[i]) * bf2f(uu[i]));
    ((uint4*)(outp + (size_t)row * 512))[lane] = pk.v;
}

// ---------------------------------------------------------------------------
// GEMM2: A2 @ W2T^T + out_b + x -> fp32. Operand-swapped -> float4 epilogue.
// ---------------------------------------------------------------------------
__global__ __launch_bounds__(256) void gemm2_kernel(const ushort* __restrict__ A,
                                                    const ushort* __restrict__ Bt,
                                                    const float* __restrict__ ob,
                                                    const float* __restrict__ x,
                                                    float* __restrict__ outp) {
    __shared__ __align__(16) ushort As[128][72];
    __shared__ __align__(16) ushort Bs[128][72];
    int tid = threadIdx.x;
    int m0 = blockIdx.x * 128, n0 = blockIdx.y * 128;
    int w = tid >> 6, lane = tid & 63;
    int wm = (w >> 1) * 64, wn = (w & 1) * 64;
    f32x4 acc[4][4] = {};
    for (int k0 = 0; k0 < Dc; k0 += 64) {
        __syncthreads();
#pragma unroll
        for (int c = tid; c < 1024; c += 256) {
            int r = c >> 3, c8 = c & 7;
            *(uint4*)&As[r][c8 * 8] = *(const uint4*)&A[(size_t)(m0 + r) * Dc + k0 + c8 * 8];
            *(uint4*)&Bs[r][c8 * 8] = *(const uint4*)&Bt[(size_t)(n0 + r) * Dc + k0 + c8 * 8];
        }
        __syncthreads();
#pragma unroll
        for (int ks = 0; ks < 2; ++ks) {
            int kb = ks * 32 + (lane >> 4) * 8;
            s16x8 af[4], bfr[4];
#pragma unroll
            for (int i = 0; i < 4; i++) af[i] = *(const s16x8*)&As[wm + i * 16 + (lane & 15)][kb];
#pragma unroll
            for (int j = 0; j < 4; j++) bfr[j] = *(const s16x8*)&Bs[wn + j * 16 + (lane & 15)][kb];
#pragma unroll
            for (int i = 0; i < 4; i++)
#pragma unroll
                for (int j = 0; j < 4; j++)
                    acc[i][j] = __builtin_amdgcn_mfma_f32_16x16x32_bf16(bfr[j], af[i], acc[i][j], 0, 0, 0);
        }
    }
    int lr = (lane >> 4) * 4, lc = lane & 15;
#pragma unroll
    for (int i = 0; i < 4; i++) {
        int m = m0 + wm + i * 16 + lc;
#pragma unroll
        for (int j = 0; j < 4; j++) {
            int col0 = n0 + wn + j * 16 + lr;
            size_t off = (size_t)m * 512 + col0;
            float4 xb = *(const float4*)&x[off];
            float4 obv = *(const float4*)&ob[col0];
            float4 o;
            o.x = acc[i][j][0] + obv.x + xb.x;
            o.y = acc[i][j][1] + obv.y + xb.y;
            o.z = acc[i][j][2] + obv.z + xb.z;
            o.w = acc[i][j][3] + obv.w + xb.w;
            *(float4*)&outp[off] = o;
        }
    }
}

// ---------------------------------------------------------------------------
extern "C" void kernel_launch(void* const* d_in, const int* in_sizes, int n_in,
                              void* d_out, int out_size, void* d_ws, size_t ws_size,
                              hipStream_t stream) {
    const float* x      = (const float*)d_in[0];
    const int*   tsp    = (const int*)d_in[1];
    // d_in[2]: attn_mask (implicit causal; unused)
    const float* uvqk_w = (const float*)d_in[3];
    const float* out_w  = (const float*)d_in[4];
    const float* out_b  = (const float*)d_in[5];
    const float* ln1_g  = (const float*)d_in[6];
    const float* ln1_b  = (const float*)d_in[7];
    const float* ln2_g  = (const float*)d_in[8];
    const float* ln2_b  = (const float*)d_in[9];
    const float* ts_w   = (const float*)d_in[10];
    const float* pos_w  = (const float*)d_in[11];
    float* outp = (float*)d_out;

    char* ws = (char*)d_ws;
    size_t off = 0;
    auto alloc = [&](size_t bytes) { char* p = ws + off; off += (bytes + 255) & ~(size_t)255; return p; };
    const size_t MAT = (size_t)ROWS * 512 * sizeof(ushort);  // 8 MB
    ushort* W1T = (ushort*)alloc((size_t)TOTAL_OUT * Dc * 2);  // 2 MB
    ushort* W2T = (ushort*)alloc((size_t)Dc * Dc * 2);         // 0.5 MB
    ushort* X1  = (ushort*)alloc(MAT);
    ushort* Ub  = (ushort*)alloc(MAT);
    ushort* VTg = (ushort*)alloc(MAT);  // V transposed: [(b*8+h)*64+d][n]
    ushort* Qb  = (ushort*)alloc(MAT);
    ushort* Kb  = (ushort*)alloc(MAT);
    ushort* Ob  = (ushort*)alloc(MAT);
    ushort* BIAS = (ushort*)alloc((size_t)Bc * Lc * Lc * 2);  // 16.8 MB
    ushort* A2  = X1;  // X1 dead after gemm1 -> reuse for ln2 output

    transpose_cast<<<dim3(TOTAL_OUT / 32, Dc / 32), 256, 0, stream>>>(uvqk_w, W1T, Dc, TOTAL_OUT);
    transpose_cast<<<dim3(Dc / 32, Dc / 32), 256, 0, stream>>>(out_w, W2T, Dc, Dc);
    bias_kernel<<<dim3(Lc / 8, Bc), 256, 0, stream>>>(tsp, pos_w, ts_w, BIAS);
    ln1_kernel<<<ROWS / 4, 256, 0, stream>>>(x, ln1_g, ln1_b, X1);
    gemm1_kernel<<<dim3(ROWS / 128, TOTAL_OUT / 128), 256, 0, stream>>>(X1, W1T, Ub, VTg, Qb, Kb);
    attn_kernel<<<dim3(8, Hc, Bc), 256, 0, stream>>>(Qb, Kb, VTg, BIAS, Ob);
    ln2_kernel<<<ROWS / 4, 256, 0, stream>>>(Ob, Ub, ln2_g, ln2_b, A2);
    gemm2_kernel<<<dim3(ROWS / 128, Dc / 128), 256, 0, stream>>>(A2, W2T, out_b, x, outp);
}

// Round 12
// 223.826 us; speedup vs baseline: 1.2273x; 1.0984x over previous
//
#include <hip/hip_runtime.h>
#include <math.h>

// Problem constants
constexpr int Bc = 8;
constexpr int Lc = 1024;
constexpr int Dc = 512;        // model dim
constexpr int Hc = 8;
constexpr int DHc = 64;
constexpr int DLc = 64;
constexpr int NBc = 128;
constexpr int TOTAL_OUT = 2 * DLc * Hc + 2 * DHc * Hc;  // 2048
constexpr int ROWS = Bc * Lc;  // 8192

using f32x4 = __attribute__((ext_vector_type(4))) float;
using s16x8 = __attribute__((ext_vector_type(8))) short;

__device__ __forceinline__ float bf2f(ushort u) {
    union { unsigned int i; float f; } v; v.i = ((unsigned int)u) << 16; return v.f;
}
__device__ __forceinline__ ushort f2bf(float f) {
    union { float f; unsigned int i; } v; v.f = f;
    unsigned int r = v.i + 0x7fffu + ((v.i >> 16) & 1u);  // RNE
    return (ushort)(r >> 16);
}
// packed f32x2 -> bf16x2 (RNE), gfx950 native
__device__ __forceinline__ unsigned int cvtpk_bf16(float lo, float hi) {
    unsigned int r;
    asm("v_cvt_pk_bf16_f32 %0, %1, %2" : "=v"(r) : "v"(lo), "v"(hi));
    return r;
}
// silu via v_exp + v_rcp (1-instr transcendentals) instead of precise divide
__device__ __forceinline__ float silu(float x) {
    float e = __expf(-x);
    return x * __builtin_amdgcn_rcpf(1.0f + e);
}
// async global->LDS, 16B per lane. LDS dest = uniform base + lane*16.
__device__ __forceinline__ void gload16(const ushort* __restrict__ g, ushort* l) {
    __builtin_amdgcn_global_load_lds(
        (const __attribute__((address_space(1))) void*)g,
        (__attribute__((address_space(3))) void*)l, 16, 0, 0);
}

// ---------------------------------------------------------------------------
// Transpose + cast fp32 (R x C) -> bf16 (C x R)
// ---------------------------------------------------------------------------
__global__ __launch_bounds__(256) void transpose_cast(const float* __restrict__ in,
                                                      ushort* __restrict__ out,
                                                      int R, int C) {
    __shared__ float tile[32][33];
    int bc = blockIdx.x * 32, br = blockIdx.y * 32;
    int tx = threadIdx.x & 31, ty = threadIdx.x >> 5;  // 32x8
    for (int i = ty; i < 32; i += 8) {
        int r = br + i, c = bc + tx;
        tile[i][tx] = (r < R && c < C) ? in[(size_t)r * C + c] : 0.f;
    }
    __syncthreads();
    for (int i = ty; i < 32; i += 8) {
        int c = bc + i, r = br + tx;
        if (c < C && r < R) out[(size_t)c * R + r] = f2bf(tile[tx][i]);
    }
}

// ---------------------------------------------------------------------------
// LN1: x (ROWS x 512 fp32) -> bf16 normalized. One wave per row.
// ---------------------------------------------------------------------------
__global__ __launch_bounds__(256) void ln1_kernel(const float* __restrict__ x,
                                                  const float* __restrict__ g,
                                                  const float* __restrict__ bta,
                                                  ushort* __restrict__ outp) {
    int wid = threadIdx.x >> 6, lane = threadIdx.x & 63;
    int row = blockIdx.x * 4 + wid;
    const float4* xr = (const float4*)(x + (size_t)row * Dc);
    float4 a = xr[lane * 2], c = xr[lane * 2 + 1];
    float xv[8] = {a.x, a.y, a.z, a.w, c.x, c.y, c.z, c.w};
    float s = 0.f, q = 0.f;
#pragma unroll
    for (int i = 0; i < 8; i++) { s += xv[i]; q += xv[i] * xv[i]; }
#pragma unroll
    for (int off = 32; off; off >>= 1) { s += __shfl_xor(s, off); q += __shfl_xor(q, off); }
    float mean = s * (1.f / 512.f);
    float var  = q * (1.f / 512.f) - mean * mean;
    float rstd = rsqrtf(var + 1e-6f);
    const float4* gv = (const float4*)g; const float4* bv = (const float4*)bta;
    float4 g0 = gv[lane * 2], g1 = gv[lane * 2 + 1];
    float4 b0 = bv[lane * 2], b1 = bv[lane * 2 + 1];
    float G[8] = {g0.x, g0.y, g0.z, g0.w, g1.x, g1.y, g1.z, g1.w};
    float Bv[8] = {b0.x, b0.y, b0.z, b0.w, b1.x, b1.y, b1.z, b1.w};
    union { ushort u16[8]; uint4 v; } pk;
#pragma unroll
    for (int i = 0; i < 8; i++) pk.u16[i] = f2bf((xv[i] - mean) * rstd * G[i] + Bv[i]);
    ((uint4*)(outp + (size_t)row * Dc))[lane] = pk.v;
}

// ---------------------------------------------------------------------------
// Bias precompute: bias[b][m][n] = pos_w[L-1+n-m] + ts_w[bucket(ts[m+1]-ts[n])]
// ---------------------------------------------------------------------------
__global__ __launch_bounds__(256) void bias_kernel(const int* __restrict__ ts,
                                                   const float* __restrict__ pos_w,
                                                   const float* __restrict__ ts_w,
                                                   ushort* __restrict__ biasb) {
    __shared__ float posw[2 * Lc - 1];
    __shared__ float tsw[NBc + 1];
    int tid = threadIdx.x;
    int b = blockIdx.y;
    for (int i = tid; i < 2 * Lc - 1; i += 256) posw[i] = pos_w[i];
    if (tid < NBc + 1) tsw[tid] = ts_w[tid];
    __syncthreads();
    int m = blockIdx.x * 8 + (tid >> 5);
    int n0 = (tid & 31) * 32;
    const int* tsb = ts + b * Lc;
    int mp = m + 1 < Lc ? m + 1 : Lc - 1;
    int tsm = tsb[mp];
    int pbase = (Lc - 1) + n0 - m;
    union { ushort u16[32]; uint4 v[4]; } o;
#pragma unroll
    for (int i = 0; i < 32; i += 4) {
        int4 tn = *(const int4*)&tsb[n0 + i];
        int dv[4] = {tsm - tn.x, tsm - tn.y, tsm - tn.z, tsm - tn.w};
#pragma unroll
        for (int e = 0; e < 4; e++) {
            float mag = fmaxf(fabsf((float)dv[e]), 1.f);
            int bkt = (int)(__log2f(mag) * 2.3028147f);  // ln(mag)/0.301
            bkt = bkt < 0 ? 0 : (bkt > NBc ? NBc : bkt);
            o.u16[i + e] = f2bf(posw[pbase + i + e] + tsw[bkt]);
        }
    }
    uint4* dst = (uint4*)&biasb[((size_t)b * Lc + m) * Lc + n0];
#pragma unroll
    for (int i = 0; i < 4; i++) dst[i] = o.v[i];
}

// ---------------------------------------------------------------------------
// GEMM1: X1 @ W1T^T -> silu -> split-store. global_load_lds(16B) staging into
// linear LDS with pre-swizzled global source (conflict-free swizzled reads).
// 128x128 tile, BK=64. Operand-swapped mfma -> vectorized ushort4 stores.
// ---------------------------------------------------------------------------
__global__ __launch_bounds__(256) void gemm1_kernel(const ushort* __restrict__ A,
                                                    const ushort* __restrict__ Bt,
                                                    ushort* __restrict__ Ub,
                                                    ushort* __restrict__ VTg,
                                                    ushort* __restrict__ Qb,
                                                    ushort* __restrict__ Kb) {
    __shared__ __align__(16) ushort As[128][64];
    __shared__ __align__(16) ushort Bs[128][64];
    int tid = threadIdx.x;
    int m0 = blockIdx.x * 128, n0 = blockIdx.y * 128;
    int w = tid >> 6, lane = tid & 63;
    int wm = (w >> 1) * 64, wn = (w & 1) * 64;
    // staging geometry: instr t covers LDS rows t*8..t*8+7; lane -> row t*8+(lane>>3),
    // LDS 16B-slot (lane&7). Source col slot pre-swizzled: (lane&7)^(lane>>3).
    int grow = lane >> 3;
    int gcol = ((lane & 7) ^ grow) * 8;
    // read-side swizzle: slot = (ks*4+g4) ^ (lane&7)
    int lc15 = lane & 15, g4 = lane >> 4;
    f32x4 acc[4][4] = {};
    for (int k0 = 0; k0 < Dc; k0 += 64) {
        __syncthreads();
#pragma unroll
        for (int it = 0; it < 4; ++it) {
            int t = w * 4 + it;
            int row = t * 8 + grow;
            gload16(&A[(size_t)(m0 + row) * Dc + k0 + gcol], &As[0][0] + t * 512);
            gload16(&Bt[(size_t)(n0 + row) * Dc + k0 + gcol], &Bs[0][0] + t * 512);
        }
        __syncthreads();
#pragma unroll
        for (int ks = 0; ks < 2; ++ks) {
            int kb = (((ks * 4 + g4) ^ (lane & 7)) * 8);
            s16x8 af[4], bfr[4];
#pragma unroll
            for (int i = 0; i < 4; i++) af[i] = *(const s16x8*)&As[wm + i * 16 + lc15][kb];
#pragma unroll
            for (int j = 0; j < 4; j++) bfr[j] = *(const s16x8*)&Bs[wn + j * 16 + lc15][kb];
#pragma unroll
            for (int i = 0; i < 4; i++)
#pragma unroll
                for (int j = 0; j < 4; j++)
                    acc[i][j] = __builtin_amdgcn_mfma_f32_16x16x32_bf16(bfr[j], af[i], acc[i][j], 0, 0, 0);
        }
    }
    // swapped layout: per-lane m fixed (lane&15), reg r = consecutive n
    int lr = (lane >> 4) * 4, lc = lane & 15;
#pragma unroll
    for (int i = 0; i < 4; i++) {
        int m = m0 + wm + i * 16 + lc;
#pragma unroll
        for (int j = 0; j < 4; j++) {
            int col0 = n0 + wn + j * 16 + lr;
            int sect = col0 >> 9, cc0 = col0 & 511;
            if (sect == 1) {
                // V: VT[d][n]; d = cc0..cc0+3 (stride 1024), n = m
                int hh = cc0 >> 6, dd0 = cc0 & 63;
                int bb = m >> 10, nn = m & 1023;
                size_t base = ((size_t)((bb * 8 + hh) * 64 + dd0)) * 1024 + nn;
#pragma unroll
                for (int r = 0; r < 4; r++)
                    VTg[base + (size_t)r * 1024] = f2bf(silu(acc[i][j][r]));
            } else {
                ushort* dst = (sect == 0) ? Ub : (sect == 2) ? Qb : Kb;
                ushort4 pk;
                pk.x = f2bf(silu(acc[i][j][0]));
                pk.y = f2bf(silu(acc[i][j][1]));
                pk.z = f2bf(silu(acc[i][j][2]));
                pk.w = f2bf(silu(acc[i][j][3]));
                *(ushort4*)&dst[(size_t)m * 512 + cc0] = pk;
            }
        }
    }
}

// ---------------------------------------------------------------------------
// Fused causal attention: paired-tile uniform blocks. (FROZEN from round 11)
// ---------------------------------------------------------------------------
__global__ __launch_bounds__(256) void attn_kernel(const ushort* __restrict__ Qb,
                                                   const ushort* __restrict__ Kb,
                                                   const ushort* __restrict__ VTg,
                                                   const ushort* __restrict__ biasb,
                                                   ushort* __restrict__ Ob) {
    int iA = blockIdx.x;       // 0..7
    int iB = 15 - iA;          // 8..15
    int h = blockIdx.y, b = blockIdx.z;
    __shared__ __align__(16) ushort Ks[2][64][64];      // 16 KB, XOR-swizzled
    __shared__ __align__(16) ushort Ps[4][2][16][64];   // 16 KB, wave-private
    int tid = threadIdx.x, w = tid >> 6, lane = tid & 63;
    const size_t qkbase = ((size_t)b * Lc) * 512 + h * 64;
    const size_t vtbase = ((size_t)((b * 8 + h) * 64)) * 1024;
    const ushort* biasT = biasb + (size_t)b * Lc * Lc;
    int lc = lane & 15, g4 = lane >> 4;
    int sr = tid >> 2;               // tile row 0..63
    int ss0 = (tid & 3) * 2;         // 16B-slot 0,2,4,6
    const ushort* kgrow = Kb + qkbase + (size_t)sr * 512;
    int dso0 = sr * 64 + (((ss0)     ^ (sr & 7)) * 8);
    int dso1 = sr * 64 + (((ss0 + 1) ^ (sr & 7)) * 8);

    // prologue: stage K(0) into Ks[0]
    {
        uint4 ka = *(const uint4*)(kgrow + ss0 * 8);
        uint4 kb_ = *(const uint4*)(kgrow + (ss0 + 1) * 8);
        *(uint4*)&(&Ks[0][0][0])[dso0] = ka;
        *(uint4*)&(&Ks[0][0][0])[dso1] = kb_;
    }
    __syncthreads();

    const int m0A = iA * 64, m0B = iB * 64;
    const int mloc = w * 16 + lc;
    const int mrowA = m0A + mloc, mrowB = m0B + mloc;
    s16x8 qfA[2], qfB[2];
#pragma unroll
    for (int ks = 0; ks < 2; ++ks) {
        qfA[ks] = *(const s16x8*)&Qb[qkbase + (size_t)mrowA * 512 + ks * 32 + g4 * 8];
        qfB[ks] = *(const s16x8*)&Qb[qkbase + (size_t)mrowB * 512 + ks * 32 + g4 * 8];
    }
    ushort* psA = &Ps[w][0][0][0];
    ushort* psB = &Ps[w][1][0][0];
    f32x4 accA[4] = {}, accB[4] = {};
    int cur = 0;
    for (int nt = 0; nt <= iB; ++nt) {
        int n0 = nt * 64;
        bool aact = (nt <= iA);
        s16x8 vb[2][4];
#pragma unroll
        for (int ks = 0; ks < 2; ++ks)
#pragma unroll
            for (int j = 0; j < 4; j++)
                vb[ks][j] = *(const s16x8*)&VTg[vtbase + (size_t)(j * 16 + lc) * 1024 + n0 + ks * 32 + g4 * 8];
        ushort4 bsvB[4], bsvA[4];
#pragma unroll
        for (int j = 0; j < 4; j++)
            bsvB[j] = *(const ushort4*)&biasT[(size_t)mrowB * Lc + n0 + j * 16 + g4 * 4];
        if (aact) {
#pragma unroll
            for (int j = 0; j < 4; j++)
                bsvA[j] = *(const ushort4*)&biasT[(size_t)mrowA * Lc + n0 + j * 16 + g4 * 4];
        }
        bool hasnext = (nt < iB);
        uint4 ka = {}, kb_ = {};
        if (hasnext) {
            const ushort* kgn = kgrow + (size_t)(n0 + 64) * 512;
            ka  = *(const uint4*)(kgn + ss0 * 8);
            kb_ = *(const uint4*)(kgn + (ss0 + 1) * 8);
        }
        const ushort* ksb = &Ks[cur][0][0];
        f32x4 sB[4] = {}, sA[4] = {};
#pragma unroll
        for (int ks = 0; ks < 2; ++ks) {
            s16x8 kf[4];
#pragma unroll
            for (int j = 0; j < 4; j++)
                kf[j] = *(const s16x8*)&ksb[(j * 16 + lc) * 64 + (((ks * 4 + g4) ^ (lc & 7)) * 8)];
#pragma unroll
            for (int j = 0; j < 4; j++) {
                sB[j] = __builtin_amdgcn_mfma_f32_16x16x32_bf16(kf[j], qfB[ks], sB[j], 0, 0, 0);
                if (aact)
                    sA[j] = __builtin_amdgcn_mfma_f32_16x16x32_bf16(kf[j], qfA[ks], sA[j], 0, 0, 0);
            }
        }
        {
            bool diag = (nt == iB);
#pragma unroll
            for (int j = 0; j < 4; j++) {
                const ushort* bp = (const ushort*)&bsvB[j];
                float p[4];
#pragma unroll
                for (int r = 0; r < 4; r++) {
                    float sv = sB[j][r] + bf2f(bp[r]);
                    float val = silu(sv) * (1.f / (float)Lc);
                    if (diag && (j * 16 + g4 * 4 + r) > mloc) val = 0.f;
                    p[r] = val;
                }
                unsigned int w0 = cvtpk_bf16(p[0], p[1]);
                unsigned int w1 = cvtpk_bf16(p[2], p[3]);
                int slot16 = j * 2 + (g4 >> 1);
                int off = lc * 64 + ((slot16 ^ (lc & 7)) * 8) + (g4 & 1) * 4;
                *(uint2*)&psB[off] = make_uint2(w0, w1);
            }
        }
        if (aact) {
            bool diag = (nt == iA);
#pragma unroll
            for (int j = 0; j < 4; j++) {
                const ushort* bp = (const ushort*)&bsvA[j];
                float p[4];
#pragma unroll
                for (int r = 0; r < 4; r++) {
                    float sv = sA[j][r] + bf2f(bp[r]);
                    float val = silu(sv) * (1.f / (float)Lc);
                    if (diag && (j * 16 + g4 * 4 + r) > mloc) val = 0.f;
                    p[r] = val;
                }
                unsigned int w0 = cvtpk_bf16(p[0], p[1]);
                unsigned int w1 = cvtpk_bf16(p[2], p[3]);
                int slot16 = j * 2 + (g4 >> 1);
                int off = lc * 64 + ((slot16 ^ (lc & 7)) * 8) + (g4 & 1) * 4;
                *(uint2*)&psA[off] = make_uint2(w0, w1);
            }
        }
#pragma unroll
        for (int ks = 0; ks < 2; ++ks) {
            int rs = ks * 4 + g4;
            s16x8 paB = *(const s16x8*)&psB[lc * 64 + ((rs ^ (lc & 7)) * 8)];
#pragma unroll
            for (int j = 0; j < 4; j++)
                accB[j] = __builtin_amdgcn_mfma_f32_16x16x32_bf16(paB, vb[ks][j], accB[j], 0, 0, 0);
            if (aact) {
                s16x8 paA = *(const s16x8*)&psA[lc * 64 + ((rs ^ (lc & 7)) * 8)];
#pragma unroll
                for (int j = 0; j < 4; j++)
                    accA[j] = __builtin_amdgcn_mfma_f32_16x16x32_bf16(paA, vb[ks][j], accA[j], 0, 0, 0);
            }
        }
        if (hasnext) {
            ushort* kd = &Ks[cur ^ 1][0][0];
            *(uint4*)&kd[dso0] = ka;
            *(uint4*)&kd[dso1] = kb_;
        }
        __syncthreads();
        cur ^= 1;
    }
    int mbA = m0A + w * 16 + g4 * 4;
    int mbB = m0B + w * 16 + g4 * 4;
#pragma unroll
    for (int j = 0; j < 4; j++)
#pragma unroll
        for (int r = 0; r < 4; r++) {
            Ob[qkbase + (size_t)(mbA + r) * 512 + j * 16 + lc] = f2bf(accA[j][r]);
            Ob[qkbase + (size_t)(mbB + r) * 512 + j * 16 + lc] = f2bf(accB[j][r]);
        }
}

// ---------------------------------------------------------------------------
// LN2(attn) * u -> bf16. One wave per row.
// ---------------------------------------------------------------------------
__global__ __launch_bounds__(256) void ln2_kernel(const ushort* __restrict__ z,
                                                  const ushort* __restrict__ u,
                                                  const float* __restrict__ g,
                                                  const float* __restrict__ bta,
                                                  ushort* __restrict__ outp) {
    int wid = threadIdx.x >> 6, lane = threadIdx.x & 63;
    int row = blockIdx.x * 4 + wid;
    uint4 zv = ((const uint4*)(z + (size_t)row * 512))[lane];
    ushort* zu = (ushort*)&zv;
    float xv[8], s = 0.f, q = 0.f;
#pragma unroll
    for (int i = 0; i < 8; i++) { xv[i] = bf2f(zu[i]); s += xv[i]; q += xv[i] * xv[i]; }
#pragma unroll
    for (int off = 32; off; off >>= 1) { s += __shfl_xor(s, off); q += __shfl_xor(q, off); }
    float mean = s * (1.f / 512.f);
    float var  = q * (1.f / 512.f) - mean * mean;
    float rstd = rsqrtf(var + 1e-6f);
    uint4 uv = ((const uint4*)(u + (size_t)row * 512))[lane];
    ushort* uu = (ushort*)&uv;
    const float4* gv = (const float4*)g; const float4* bv = (const float4*)bta;
    float4 g0 = gv[lane * 2], g1 = gv[lane * 2 + 1];
    float4 b0 = bv[lane * 2], b1 = bv[lane * 2 + 1];
    float G[8] = {g0.x, g0.y, g0.z, g0.w, g1.x, g1.y, g1.z, g1.w};
    float Bv[8] = {b0.x, b0.y, b0.z, b0.w, b1.x, b1.y, b1.z, b1.w};
    union { ushort u16[8]; uint4 v; } pk;
#pragma unroll
    for (int i = 0; i < 8; i++)
        pk.u16[i] = f2bf(((xv[i] - mean) * rstd * G[i] + Bv[i]) * bf2f(uu[i]));
    ((uint4*)(outp + (size_t)row * 512))[lane] = pk.v;
}

// ---------------------------------------------------------------------------
// GEMM2: A2 @ W2T^T + out_b + x -> fp32. 64x128 tile (512 blocks, 2/CU),
// global_load_lds staging, swizzled reads, float4 epilogue.
// ---------------------------------------------------------------------------
__global__ __launch_bounds__(256) void gemm2_kernel(const ushort* __restrict__ A,
                                                    const ushort* __restrict__ Bt,
                                                    const float* __restrict__ ob,
                                                    const float* __restrict__ x,
                                                    float* __restrict__ outp) {
    __shared__ __align__(16) ushort As[64][64];
    __shared__ __align__(16) ushort Bs[128][64];
    int tid = threadIdx.x;
    int m0 = blockIdx.x * 64, n0 = blockIdx.y * 128;
    int w = tid >> 6, lane = tid & 63;
    int wm = (w >> 1) * 32, wn = (w & 1) * 64;
    int grow = lane >> 3;
    int gcol = ((lane & 7) ^ grow) * 8;
    int lc15 = lane & 15, g4 = lane >> 4;
    f32x4 acc[2][4] = {};
    for (int k0 = 0; k0 < Dc; k0 += 64) {
        __syncthreads();
#pragma unroll
        for (int it = 0; it < 2; ++it) {
            int t = w * 2 + it;
            int row = t * 8 + grow;
            gload16(&A[(size_t)(m0 + row) * Dc + k0 + gcol], &As[0][0] + t * 512);
        }
#pragma unroll
        for (int it = 0; it < 4; ++it) {
            int t = w * 4 + it;
            int row = t * 8 + grow;
            gload16(&Bt[(size_t)(n0 + row) * Dc + k0 + gcol], &Bs[0][0] + t * 512);
        }
        __syncthreads();
#pragma unroll
        for (int ks = 0; ks < 2; ++ks) {
            int kb = (((ks * 4 + g4) ^ (lane & 7)) * 8);
            s16x8 af[2], bfr[4];
#pragma unroll
            for (int i = 0; i < 2; i++) af[i] = *(const s16x8*)&As[wm + i * 16 + lc15][kb];
#pragma unroll
            for (int j = 0; j < 4; j++) bfr[j] = *(const s16x8*)&Bs[wn + j * 16 + lc15][kb];
#pragma unroll
            for (int i = 0; i < 2; i++)
#pragma unroll
                for (int j = 0; j < 4; j++)
                    acc[i][j] = __builtin_amdgcn_mfma_f32_16x16x32_bf16(bfr[j], af[i], acc[i][j], 0, 0, 0);
        }
    }
    int lr = (lane >> 4) * 4, lc = lane & 15;
#pragma unroll
    for (int i = 0; i < 2; i++) {
        int m = m0 + wm + i * 16 + lc;
#pragma unroll
        for (int j = 0; j < 4; j++) {
            int col0 = n0 + wn + j * 16 + lr;
            size_t off = (size_t)m * 512 + col0;
            float4 xb = *(const float4*)&x[off];
            float4 obv = *(const float4*)&ob[col0];
            float4 o;
            o.x = acc[i][j][0] + obv.x + xb.x;
            o.y = acc[i][j][1] + obv.y + xb.y;
            o.z = acc[i][j][2] + obv.z + xb.z;
            o.w = acc[i][j][3] + obv.w + xb.w;
            *(float4*)&outp[off] = o;
        }
    }
}

// ---------------------------------------------------------------------------
extern "C" void kernel_launch(void* const* d_in, const int* in_sizes, int n_in,
                              void* d_out, int out_size, void* d_ws, size_t ws_size,
                              hipStream_t stream) {
    const float* x      = (const float*)d_in[0];
    const int*   tsp    = (const int*)d_in[1];
    // d_in[2]: attn_mask (implicit causal; unused)
    const float* uvqk_w = (const float*)d_in[3];
    const float* out_w  = (const float*)d_in[4];
    const float* out_b  = (const float*)d_in[5];
    const float* ln1_g  = (const float*)d_in[6];
    const float* ln1_b  = (const float*)d_in[7];
    const float* ln2_g  = (const float*)d_in[8];
    const float* ln2_b  = (const float*)d_in[9];
    const float* ts_w   = (const float*)d_in[10];
    const float* pos_w  = (const float*)d_in[11];
    float* outp = (float*)d_out;

    char* ws = (char*)d_ws;
    size_t off = 0;
    auto alloc = [&](size_t bytes) { char* p = ws + off; off += (bytes + 255) & ~(size_t)255; return p; };
    const size_t MAT = (size_t)ROWS * 512 * sizeof(ushort);  // 8 MB
    ushort* W1T = (ushort*)alloc((size_t)TOTAL_OUT * Dc * 2);  // 2 MB
    ushort* W2T = (ushort*)alloc((size_t)Dc * Dc * 2);         // 0.5 MB
    ushort* X1  = (ushort*)alloc(MAT);
    ushort* Ub  = (ushort*)alloc(MAT);
    ushort* VTg = (ushort*)alloc(MAT);  // V transposed: [(b*8+h)*64+d][n]
    ushort* Qb  = (ushort*)alloc(MAT);
    ushort* Kb  = (ushort*)alloc(MAT);
    ushort* Ob  = (ushort*)alloc(MAT);
    ushort* BIAS = (ushort*)alloc((size_t)Bc * Lc * Lc * 2);  // 16.8 MB
    ushort* A2  = X1;  // X1 dead after gemm1 -> reuse for ln2 output

    transpose_cast<<<dim3(TOTAL_OUT / 32, Dc / 32), 256, 0, stream>>>(uvqk_w, W1T, Dc, TOTAL_OUT);
    transpose_cast<<<dim3(Dc / 32, Dc / 32), 256, 0, stream>>>(out_w, W2T, Dc, Dc);
    bias_kernel<<<dim3(Lc / 8, Bc), 256, 0, stream>>>(tsp, pos_w, ts_w, BIAS);
    ln1_kernel<<<ROWS / 4, 256, 0, stream>>>(x, ln1_g, ln1_b, X1);
    gemm1_kernel<<<dim3(ROWS / 128, TOTAL_OUT / 128), 256, 0, stream>>>(X1, W1T, Ub, VTg, Qb, Kb);
    attn_kernel<<<dim3(8, Hc, Bc), 256, 0, stream>>>(Qb, Kb, VTg, BIAS, Ob);
    ln2_kernel<<<ROWS / 4, 256, 0, stream>>>(Ob, Ub, ln2_g, ln2_b, A2);
    gemm2_kernel<<<dim3(ROWS / 64, Dc / 128), 256, 0, stream>>>(A2, W2T, out_b, x, outp);
}